// Round 1
// baseline (816.358 us; speedup 1.0000x reference)
//
#include <hip/hip_runtime.h>
#include <math.h>

// Problem constants (fixed by the reference).
#define NN     50000
#define FF     256
#define HH     64
#define NHEADS 4
#define EE     800000
#define OUTD   16

// ---------------------------------------------------------------------------
// CSR build: count in-degree, exclusive scan, fill column (src) lists.
// Self-loops are NOT stored; every per-node kernel handles src=dst explicitly.
// ---------------------------------------------------------------------------
__global__ void k_zero_int(int* __restrict__ p, int n) {
    int i = blockIdx.x * blockDim.x + threadIdx.x;
    if (i < n) p[i] = 0;
}

__global__ void k_count(const int* __restrict__ dst, int* __restrict__ cnt, int e) {
    int i = blockIdx.x * blockDim.x + threadIdx.x;
    if (i < e) atomicAdd(&cnt[dst[i]], 1);
}

// Single-block scan over N=50000 (chunk-per-thread + Hillis-Steele on 1024
// partials). Also emits dinv = rsqrt(deg+1) (self-loop augmented degree).
__global__ __launch_bounds__(1024) void k_scan(const int* __restrict__ cnt,
                                               int* __restrict__ row_start,
                                               int* __restrict__ cursor,
                                               float* __restrict__ dinv, int n) {
    __shared__ int part[1024];
    int tid = threadIdx.x;
    int chunk = (n + 1023) >> 10;
    int beg = tid * chunk;
    int end = min(beg + chunk, n);
    int s = 0;
    for (int i = beg; i < end; i++) s += cnt[i];
    part[tid] = s;
    __syncthreads();
    for (int off = 1; off < 1024; off <<= 1) {
        int v = part[tid];
        int add = (tid >= off) ? part[tid - off] : 0;
        __syncthreads();
        part[tid] = v + add;
        __syncthreads();
    }
    int base = (tid > 0) ? part[tid - 1] : 0;
    for (int i = beg; i < end; i++) {
        int c = cnt[i];
        row_start[i] = base;
        cursor[i] = base;
        dinv[i] = rsqrtf((float)(c + 1));
        base += c;
    }
    if (tid == 0) row_start[n] = part[1023];
}

__global__ void k_fill(const int* __restrict__ src, const int* __restrict__ dst,
                       int* __restrict__ cursor, int* __restrict__ col, int e) {
    int i = blockIdx.x * blockDim.x + threadIdx.x;
    if (i < e) {
        int d = dst[i];
        int pos = atomicAdd(&cursor[d], 1);
        col[pos] = src[i];
    }
}

// ---------------------------------------------------------------------------
// GEMM, 64-col tiles: C[M,KOUT] = A[M,KIN] @ W[KIN,KOUT], block = 64 rows x
// 64 cols (blockIdx.y selects the 64-col slab), 256 threads, 4x4 per thread.
// ---------------------------------------------------------------------------
template <int KIN>
__global__ __launch_bounds__(256) void gemm64(const float* __restrict__ A,
                                              const float* __restrict__ W,
                                              float* __restrict__ C, int M, int ldw) {
    __shared__ float As[16][64];  // As[k][m]
    __shared__ float Ws[16][64];  // Ws[k][n]
    int tid = threadIdx.x;
    int row0 = blockIdx.x * 64;
    int col0 = blockIdx.y * 64;
    int tx = tid & 15;   // col group (4 cols)
    int ty = tid >> 4;   // row group (4 rows)
    int lm = tid >> 2;          // A-load row 0..63
    int lk = (tid & 3) * 4;     // A-load k 0,4,8,12
    int wk = tid >> 4;          // W-load k 0..15
    int wn = (tid & 15) * 4;    // W-load n 0..60
    float acc[4][4] = {};

    for (int k0 = 0; k0 < KIN; k0 += 16) {
        float4 av = make_float4(0.f, 0.f, 0.f, 0.f);
        if (row0 + lm < M)
            av = *(const float4*)(A + (size_t)(row0 + lm) * KIN + k0 + lk);
        float4 wv = *(const float4*)(W + (size_t)(k0 + wk) * ldw + col0 + wn);
        __syncthreads();  // previous tile's readers done
        As[lk + 0][lm] = av.x;
        As[lk + 1][lm] = av.y;
        As[lk + 2][lm] = av.z;
        As[lk + 3][lm] = av.w;
        *(float4*)&Ws[wk][wn] = wv;
        __syncthreads();
#pragma unroll
        for (int kk = 0; kk < 16; kk++) {
            float4 a = *(const float4*)&As[kk][ty * 4];
            float4 w = *(const float4*)&Ws[kk][tx * 4];
            acc[0][0] += a.x * w.x; acc[0][1] += a.x * w.y; acc[0][2] += a.x * w.z; acc[0][3] += a.x * w.w;
            acc[1][0] += a.y * w.x; acc[1][1] += a.y * w.y; acc[1][2] += a.y * w.z; acc[1][3] += a.y * w.w;
            acc[2][0] += a.z * w.x; acc[2][1] += a.z * w.y; acc[2][2] += a.z * w.z; acc[2][3] += a.z * w.w;
            acc[3][0] += a.w * w.x; acc[3][1] += a.w * w.y; acc[3][2] += a.w * w.z; acc[3][3] += a.w * w.w;
        }
    }
#pragma unroll
    for (int i = 0; i < 4; i++) {
        int r = row0 + ty * 4 + i;
        if (r < M)
            *(float4*)(C + (size_t)r * ldw + col0 + tx * 4) =
                make_float4(acc[i][0], acc[i][1], acc[i][2], acc[i][3]);
    }
}

// GEMM with KOUT=16: W (KIN x 16) lives in LDS, one thread per output elem.
template <int KIN>
__global__ __launch_bounds__(256) void gemm_n16(const float* __restrict__ A,
                                                const float* __restrict__ W,
                                                float* __restrict__ C, int M) {
    __shared__ float Ws[KIN * 16];
    for (int i = threadIdx.x; i < KIN * 16; i += 256) Ws[i] = W[i];
    __syncthreads();
    int t = blockIdx.x * 256 + threadIdx.x;
    int row = t >> 4;
    int c = t & 15;
    if (row >= M) return;
    const float* a = A + (size_t)row * KIN;
    float acc = 0.f;
#pragma unroll 8
    for (int k = 0; k < KIN; k += 4) {
        float4 av = *(const float4*)(a + k);
        acc += av.x * Ws[(k + 0) * 16 + c];
        acc += av.y * Ws[(k + 1) * 16 + c];
        acc += av.z * Ws[(k + 2) * 16 + c];
        acc += av.w * Ws[(k + 3) * 16 + c];
    }
    C[(size_t)row * 16 + c] = acc;
}

// ---------------------------------------------------------------------------
// GCN aggregations (CSR gather, one wave per dst for 64-wide, 16 lanes/node
// for 16-wide). out = sum_{src in N(dst)} h[src]*dinv[src]*dinv[dst] + self.
// ---------------------------------------------------------------------------
__global__ __launch_bounds__(256) void gcn1_agg(const float* __restrict__ h,
                                                const int* __restrict__ rs,
                                                const int* __restrict__ col,
                                                const float* __restrict__ dinv,
                                                const float* __restrict__ b,
                                                float* __restrict__ out) {
    int wid = (blockIdx.x * 256 + threadIdx.x) >> 6;
    int lane = threadIdx.x & 63;
    if (wid >= NN) return;
    float di = dinv[wid];
    int beg = rs[wid], end = rs[wid + 1];
    float acc = h[(size_t)wid * HH + lane] * di * di;  // self loop
    for (int j = beg; j < end; j++) {
        int s = col[j];
        acc += h[(size_t)s * HH + lane] * (dinv[s] * di);
    }
    float v = acc + b[lane];
    out[(size_t)wid * HH + lane] = fmaxf(v, 0.f);  // relu(gcn1)
}

__global__ __launch_bounds__(256) void gcn2_agg(const float* __restrict__ h,
                                                const int* __restrict__ rs,
                                                const int* __restrict__ col,
                                                const float* __restrict__ dinv,
                                                const float* __restrict__ b,
                                                float* __restrict__ out /* d_out */) {
    int t = blockIdx.x * 256 + threadIdx.x;
    int node = t >> 4;
    int c = t & 15;
    if (node >= NN) return;
    float di = dinv[node];
    int beg = rs[node], end = rs[node + 1];
    float acc = h[(size_t)node * 16 + c] * di * di;
    for (int j = beg; j < end; j++) {
        int s = col[j];
        acc += h[(size_t)s * 16 + c] * (dinv[s] * di);
    }
    out[(size_t)node * 32 + c] = acc + b[c];  // no relu; cols 0..15
}

// ---------------------------------------------------------------------------
// GAT layer 1: per-node attention scores then online-softmax aggregation.
// ---------------------------------------------------------------------------
__global__ __launch_bounds__(256) void s1_kernel(const float* __restrict__ hg,
                                                 const float* __restrict__ a_s,
                                                 const float* __restrict__ a_d,
                                                 float* __restrict__ ssrc,
                                                 float* __restrict__ sdst) {
    int wid = (blockIdx.x * 256 + threadIdx.x) >> 6;
    int lane = threadIdx.x & 63;
    if (wid >= NN) return;
    float ss[4], sd[4];
#pragma unroll
    for (int h = 0; h < 4; h++) {
        float v = hg[(size_t)wid * 256 + h * 64 + lane];
        float ps = v * a_s[h * 64 + lane];
        float pd = v * a_d[h * 64 + lane];
        for (int off = 32; off >= 1; off >>= 1) {
            ps += __shfl_xor(ps, off, 64);
            pd += __shfl_xor(pd, off, 64);
        }
        ss[h] = ps;
        sd[h] = pd;
    }
    if (lane == 0) {
        *(float4*)(ssrc + (size_t)wid * 4) = make_float4(ss[0], ss[1], ss[2], ss[3]);
        *(float4*)(sdst + (size_t)wid * 4) = make_float4(sd[0], sd[1], sd[2], sd[3]);
    }
}

__global__ __launch_bounds__(256) void gat1_agg(const float* __restrict__ hg,
                                                const int* __restrict__ rs,
                                                const int* __restrict__ col,
                                                const float* __restrict__ ssrc,
                                                const float* __restrict__ sdst,
                                                const float* __restrict__ b,
                                                float* __restrict__ out) {
    int wid = (blockIdx.x * 256 + threadIdx.x) >> 6;
    int lane = threadIdx.x & 63;
    if (wid >= NN) return;
    float4 sd4 = *(const float4*)(sdst + (size_t)wid * 4);
    float sd[4] = {sd4.x, sd4.y, sd4.z, sd4.w};
    float m[4] = {-INFINITY, -INFINITY, -INFINITY, -INFINITY};
    float l[4] = {0.f, 0.f, 0.f, 0.f};
    float acc[4] = {0.f, 0.f, 0.f, 0.f};
    int beg = rs[wid], end = rs[wid + 1];
    // j == beg-1 is the self loop (src = wid).
    for (int j = beg - 1; j < end; j++) {
        int s = (j < beg) ? wid : col[j];
        float4 sv = *(const float4*)(ssrc + (size_t)s * 4);
        float e[4] = {sv.x + sd[0], sv.y + sd[1], sv.z + sd[2], sv.w + sd[3]};
#pragma unroll
        for (int h = 0; h < 4; h++) {
            float ee = e[h];
            ee = (ee >= 0.f) ? ee : 0.2f * ee;  // leaky_relu 0.2
            float mn = fmaxf(m[h], ee);
            float corr = __expf(m[h] - mn);
            float p = __expf(ee - mn);
            l[h] = l[h] * corr + p;
            float hv = hg[(size_t)s * 256 + h * 64 + lane];
            acc[h] = acc[h] * corr + hv * p;
            m[h] = mn;
        }
    }
#pragma unroll
    for (int h = 0; h < 4; h++) {
        float v = acc[h] / l[h] + b[h * 64 + lane];
        out[(size_t)wid * 256 + h * 64 + lane] = fmaxf(v, 0.f);  // relu(gat1)
    }
}

// ---------------------------------------------------------------------------
// GAT layer 2 (heads=1, C=16).
// ---------------------------------------------------------------------------
__global__ __launch_bounds__(256) void s2_kernel(const float* __restrict__ hg,
                                                 const float* __restrict__ a_s,
                                                 const float* __restrict__ a_d,
                                                 float* __restrict__ ssrc,
                                                 float* __restrict__ sdst) {
    int t = blockIdx.x * 256 + threadIdx.x;
    int node = t >> 4;
    int c = t & 15;
    if (node >= NN) return;
    float v = hg[(size_t)node * 16 + c];
    float ps = v * a_s[c];
    float pd = v * a_d[c];
    for (int off = 8; off >= 1; off >>= 1) {
        ps += __shfl_xor(ps, off, 64);
        pd += __shfl_xor(pd, off, 64);
    }
    if (c == 0) {
        ssrc[node] = ps;
        sdst[node] = pd;
    }
}

__global__ __launch_bounds__(256) void gat2_agg(const float* __restrict__ hg,
                                                const int* __restrict__ rs,
                                                const int* __restrict__ col,
                                                const float* __restrict__ ssrc,
                                                const float* __restrict__ sdst,
                                                const float* __restrict__ b,
                                                float* __restrict__ out /* d_out */) {
    int t = blockIdx.x * 256 + threadIdx.x;
    int node = t >> 4;
    int c = t & 15;
    if (node >= NN) return;
    float sd = sdst[node];
    float m = -INFINITY, l = 0.f, acc = 0.f;
    int beg = rs[node], end = rs[node + 1];
    for (int j = beg - 1; j < end; j++) {
        int s = (j < beg) ? node : col[j];
        float ee = ssrc[s] + sd;
        ee = (ee >= 0.f) ? ee : 0.2f * ee;
        float mn = fmaxf(m, ee);
        float corr = __expf(m - mn);
        float p = __expf(ee - mn);
        l = l * corr + p;
        acc = acc * corr + hg[(size_t)s * 16 + c] * p;
        m = mn;
    }
    out[(size_t)node * 32 + 16 + c] = acc / l + b[c];  // cols 16..31
}

// ---------------------------------------------------------------------------
// Launch
// ---------------------------------------------------------------------------
extern "C" void kernel_launch(void* const* d_in, const int* in_sizes, int n_in,
                              void* d_out, int out_size, void* d_ws, size_t ws_size,
                              hipStream_t stream) {
    const float* x      = (const float*)d_in[0];
    const int*   ei     = (const int*)d_in[1];   // [2, E] row-major: src then dst
    const float* Wg1    = (const float*)d_in[2];
    const float* bg1    = (const float*)d_in[3];
    const float* Wg2    = (const float*)d_in[4];
    const float* bg2    = (const float*)d_in[5];
    const float* Wgat1  = (const float*)d_in[6];
    const float* a_src1 = (const float*)d_in[7];
    const float* a_dst1 = (const float*)d_in[8];
    const float* bgat1  = (const float*)d_in[9];
    const float* Wgat2  = (const float*)d_in[10];
    const float* a_src2 = (const float*)d_in[11];
    const float* a_dst2 = (const float*)d_in[12];
    const float* bgat2  = (const float*)d_in[13];
    float* out = (float*)d_out;

    const int* e_src = ei;
    const int* e_dst = ei + EE;

    // Workspace layout (floats); every buffer fully written before read.
    float* wsf = (float*)d_ws;
    size_t o = 0;
    float* dinv    = wsf + o; o += NN;
    float* ssrc1   = wsf + o; o += (size_t)NN * 4;
    float* sdst1   = wsf + o; o += (size_t)NN * 4;
    float* buf64a  = wsf + o; o += (size_t)NN * 64;   // h1, then h2 (N*16)
    float* buf64b  = wsf + o; o += (size_t)NN * 64;   // xg1 (relu'd gcn1)
    float* buf256a = wsf + o; o += (size_t)NN * 256;  // hgat, then h2g + s2src/s2dst
    float* buf256b = wsf + o; o += (size_t)NN * 256;  // xgat1 (relu'd gat1)
    int* cnt      = (int*)(wsf + o); o += NN;
    int* rowstart = (int*)(wsf + o); o += NN + 1;
    int* cursor   = (int*)(wsf + o); o += NN;
    int* colarr   = (int*)(wsf + o); o += EE;

    float* h1   = buf64a;
    float* xg1  = buf64b;
    float* h2   = buf64a;            // reuse after h1 dead
    float* hgat = buf256a;
    float* xg_at1 = buf256b;
    float* h2g  = buf256a;           // reuse after hgat dead
    float* s2src = buf256a + (size_t)NN * 16;
    float* s2dst = s2src + NN;

    const int TB = 256;
    // --- CSR build ---
    k_zero_int<<<(NN + TB - 1) / TB, TB, 0, stream>>>(cnt, NN);
    k_count<<<(EE + TB - 1) / TB, TB, 0, stream>>>(e_dst, cnt, EE);
    k_scan<<<1, 1024, 0, stream>>>(cnt, rowstart, cursor, dinv, NN);
    k_fill<<<(EE + TB - 1) / TB, TB, 0, stream>>>(e_src, e_dst, cursor, colarr, EE);

    // --- GCN path ---
    gemm64<FF><<<dim3((NN + 63) / 64, 1), TB, 0, stream>>>(x, Wg1, h1, NN, HH);
    gcn1_agg<<<(NN * 64 + TB - 1) / TB, TB, 0, stream>>>(h1, rowstart, colarr, dinv, bg1, xg1);
    gemm_n16<HH><<<(NN * 16 + TB - 1) / TB, TB, 0, stream>>>(xg1, Wg2, h2, NN);
    gcn2_agg<<<(NN * 16 + TB - 1) / TB, TB, 0, stream>>>(h2, rowstart, colarr, dinv, bg2, out);

    // --- GAT path ---
    gemm64<FF><<<dim3((NN + 63) / 64, 4), TB, 0, stream>>>(x, Wgat1, hgat, NN, NHEADS * HH);
    s1_kernel<<<(NN * 64 + TB - 1) / TB, TB, 0, stream>>>(hgat, a_src1, a_dst1, ssrc1, sdst1);
    gat1_agg<<<(NN * 64 + TB - 1) / TB, TB, 0, stream>>>(hgat, rowstart, colarr, ssrc1, sdst1, bgat1, xg_at1);
    gemm_n16<NHEADS * HH><<<(NN * 16 + TB - 1) / TB, TB, 0, stream>>>(xg_at1, Wgat2, h2g, NN);
    s2_kernel<<<(NN * 16 + TB - 1) / TB, TB, 0, stream>>>(h2g, a_src2, a_dst2, s2src, s2dst);
    gat2_agg<<<(NN * 16 + TB - 1) / TB, TB, 0, stream>>>(h2g, rowstart, colarr, s2src, s2dst, bgat2, out);
}

// Round 3
// 735.704 us; speedup vs baseline: 1.1096x; 1.1096x over previous
//
#include <hip/hip_runtime.h>
#include <math.h>

#define NN     50000
#define FF     256
#define HH     64
#define NHEADS 4
#define EE     800000
#define OUTD   16

// ---------------------------------------------------------------------------
// CSR build
// ---------------------------------------------------------------------------
__global__ void k_zero_int(int* __restrict__ p, int n) {
    int i = blockIdx.x * blockDim.x + threadIdx.x;
    if (i < n) p[i] = 0;
}

__global__ void k_count(const int* __restrict__ dst, int* __restrict__ cnt, int e) {
    int i = blockIdx.x * blockDim.x + threadIdx.x;
    if (i < e) atomicAdd(&cnt[dst[i]], 1);
}

__global__ __launch_bounds__(1024) void k_scan(const int* __restrict__ cnt,
                                               int* __restrict__ row_start,
                                               int* __restrict__ cursor,
                                               float* __restrict__ dinv, int n) {
    __shared__ int part[1024];
    int tid = threadIdx.x;
    int chunk = (n + 1023) >> 10;
    int beg = tid * chunk;
    int end = min(beg + chunk, n);
    int s = 0;
    for (int i = beg; i < end; i++) s += cnt[i];
    part[tid] = s;
    __syncthreads();
    for (int off = 1; off < 1024; off <<= 1) {
        int v = part[tid];
        int add = (tid >= off) ? part[tid - off] : 0;
        __syncthreads();
        part[tid] = v + add;
        __syncthreads();
    }
    int base = (tid > 0) ? part[tid - 1] : 0;
    for (int i = beg; i < end; i++) {
        int c = cnt[i];
        row_start[i] = base;
        cursor[i] = base;
        dinv[i] = rsqrtf((float)(c + 1));
        base += c;
    }
    if (tid == 0) row_start[n] = part[1023];
}

__global__ void k_fill(const int* __restrict__ src, const int* __restrict__ dst,
                       int* __restrict__ cursor, int* __restrict__ col, int e) {
    int i = blockIdx.x * blockDim.x + threadIdx.x;
    if (i < e) {
        int d = dst[i];
        int pos = atomicAdd(&cursor[d], 1);
        col[pos] = src[i];
    }
}

// ---------------------------------------------------------------------------
// GEMM 64-col tiles; optional per-row output scale (folds dinv into h).
// ---------------------------------------------------------------------------
template <int KIN>
__global__ __launch_bounds__(256) void gemm64(const float* __restrict__ A,
                                              const float* __restrict__ W,
                                              float* __restrict__ C, int M, int ldw,
                                              const float* __restrict__ rowscale) {
    __shared__ float As[16][64];
    __shared__ float Ws[16][64];
    int tid = threadIdx.x;
    int row0 = blockIdx.x * 64;
    int col0 = blockIdx.y * 64;
    int tx = tid & 15;
    int ty = tid >> 4;
    int lm = tid >> 2;
    int lk = (tid & 3) * 4;
    int wk = tid >> 4;
    int wn = (tid & 15) * 4;
    float acc[4][4] = {};

    for (int k0 = 0; k0 < KIN; k0 += 16) {
        float4 av = make_float4(0.f, 0.f, 0.f, 0.f);
        if (row0 + lm < M)
            av = *(const float4*)(A + (size_t)(row0 + lm) * KIN + k0 + lk);
        float4 wv = *(const float4*)(W + (size_t)(k0 + wk) * ldw + col0 + wn);
        __syncthreads();
        As[lk + 0][lm] = av.x;
        As[lk + 1][lm] = av.y;
        As[lk + 2][lm] = av.z;
        As[lk + 3][lm] = av.w;
        *(float4*)&Ws[wk][wn] = wv;
        __syncthreads();
#pragma unroll
        for (int kk = 0; kk < 16; kk++) {
            float4 a = *(const float4*)&As[kk][ty * 4];
            float4 w = *(const float4*)&Ws[kk][tx * 4];
            acc[0][0] += a.x * w.x; acc[0][1] += a.x * w.y; acc[0][2] += a.x * w.z; acc[0][3] += a.x * w.w;
            acc[1][0] += a.y * w.x; acc[1][1] += a.y * w.y; acc[1][2] += a.y * w.z; acc[1][3] += a.y * w.w;
            acc[2][0] += a.z * w.x; acc[2][1] += a.z * w.y; acc[2][2] += a.z * w.z; acc[2][3] += a.z * w.w;
            acc[3][0] += a.w * w.x; acc[3][1] += a.w * w.y; acc[3][2] += a.w * w.z; acc[3][3] += a.w * w.w;
        }
    }
#pragma unroll
    for (int i = 0; i < 4; i++) {
        int r = row0 + ty * 4 + i;
        if (r < M) {
            float sc = rowscale ? rowscale[r] : 1.0f;
            *(float4*)(C + (size_t)r * ldw + col0 + tx * 4) =
                make_float4(acc[i][0] * sc, acc[i][1] * sc, acc[i][2] * sc, acc[i][3] * sc);
        }
    }
}

// GEMM KOUT=16, optional per-row output scale.
template <int KIN>
__global__ __launch_bounds__(256) void gemm_n16(const float* __restrict__ A,
                                                const float* __restrict__ W,
                                                float* __restrict__ C, int M,
                                                const float* __restrict__ rowscale) {
    __shared__ float Ws[KIN * 16];
    for (int i = threadIdx.x; i < KIN * 16; i += 256) Ws[i] = W[i];
    __syncthreads();
    int t = blockIdx.x * 256 + threadIdx.x;
    int row = t >> 4;
    int c = t & 15;
    if (row >= M) return;
    const float* a = A + (size_t)row * KIN;
    float acc = 0.f;
#pragma unroll 8
    for (int k = 0; k < KIN; k += 4) {
        float4 av = *(const float4*)(a + k);
        acc += av.x * Ws[(k + 0) * 16 + c];
        acc += av.y * Ws[(k + 1) * 16 + c];
        acc += av.z * Ws[(k + 2) * 16 + c];
        acc += av.w * Ws[(k + 3) * 16 + c];
    }
    float sc = rowscale ? rowscale[row] : 1.0f;
    C[(size_t)row * 16 + c] = acc * sc;
}

// ---------------------------------------------------------------------------
// GCN1 aggregation. h is PRE-SCALED by dinv[row]. One wave per node;
// 4 lane-groups of 16 process 4 edges at a time, float4 channels.
// NOTE: the __shfl MUST be unconditional — ds_bpermute reads from inactive
// source lanes are undefined (this was the round-2 bug: cnt=17-type tails
// masked off the source lane while other groups still read it).
// ---------------------------------------------------------------------------
__global__ __launch_bounds__(256) void gcn1_agg(const float* __restrict__ h,
                                                const int* __restrict__ rs,
                                                const int* __restrict__ col,
                                                const float* __restrict__ dinv,
                                                const float* __restrict__ b,
                                                float* __restrict__ out) {
    int wid = (blockIdx.x * 256 + threadIdx.x) >> 6;
    int lane = threadIdx.x & 63;
    if (wid >= NN) return;
    int g = lane >> 4;           // edge subgroup
    int cidx = (lane & 15) * 4;  // channel base
    float di = dinv[wid];
    int beg = rs[wid], end = rs[wid + 1];
    float4 acc = make_float4(0.f, 0.f, 0.f, 0.f);

    for (int j0 = beg; j0 < end; j0 += 64) {
        int cnt = min(64, end - j0);
        int sreg = 0;
        if (lane < cnt) sreg = col[j0 + lane];
        for (int e = 0; e < cnt; e += 4) {
            int myE = e + g;                    // <= 63 always (e <= 60, g <= 3)
            int s = __shfl(sreg, myE, 64);      // full-exec shfl: defined
            if (myE < cnt) {
                float4 v = *(const float4*)(h + (size_t)s * HH + cidx);
                acc.x += v.x; acc.y += v.y; acc.z += v.z; acc.w += v.w;
            }
        }
    }
    // reduce across the 4 groups (wave-uniform flow here)
#pragma unroll
    for (int off = 16; off <= 32; off <<= 1) {
        acc.x += __shfl_xor(acc.x, off, 64);
        acc.y += __shfl_xor(acc.y, off, 64);
        acc.z += __shfl_xor(acc.z, off, 64);
        acc.w += __shfl_xor(acc.w, off, 64);
    }
    if (g == 0) {
        float4 self = *(const float4*)(h + (size_t)wid * HH + cidx);
        float4 bv = *(const float4*)(b + cidx);
        float4 o;
        o.x = fmaxf((acc.x + self.x) * di + bv.x, 0.f);
        o.y = fmaxf((acc.y + self.y) * di + bv.y, 0.f);
        o.z = fmaxf((acc.z + self.z) * di + bv.z, 0.f);
        o.w = fmaxf((acc.w + self.w) * di + bv.w, 0.f);
        *(float4*)(out + (size_t)wid * HH + cidx) = o;
    }
}

// ---------------------------------------------------------------------------
// GCN2 aggregation. h (N x 16) PRE-SCALED by dinv[row]. 16 lanes per node.
// Shfl sources are always within the node's own (active) 16-lane group.
// ---------------------------------------------------------------------------
__global__ __launch_bounds__(256) void gcn2_agg(const float* __restrict__ h,
                                                const int* __restrict__ rs,
                                                const int* __restrict__ col,
                                                const float* __restrict__ dinv,
                                                const float* __restrict__ b,
                                                float* __restrict__ out) {
    int t = blockIdx.x * 256 + threadIdx.x;
    int node = t >> 4;
    int c = t & 15;
    if (node >= NN) return;
    float di = dinv[node];
    int beg = rs[node], end = rs[node + 1];
    float acc = h[(size_t)node * 16 + c];  // self (pre-scaled)
    for (int j0 = beg; j0 < end; j0 += 16) {
        int cnt = min(16, end - j0);
        int sreg = 0;
        if (c < cnt) sreg = col[j0 + c];
        for (int e = 0; e < cnt; e++) {
            int s = __shfl(sreg, e, 16);
            acc += h[(size_t)s * 16 + c];
        }
    }
    out[(size_t)node * 32 + c] = acc * di + b[c];
}

// ---------------------------------------------------------------------------
// GAT layer 1 scores
// ---------------------------------------------------------------------------
__global__ __launch_bounds__(256) void s1_kernel(const float* __restrict__ hg,
                                                 const float* __restrict__ a_s,
                                                 const float* __restrict__ a_d,
                                                 float* __restrict__ ssrc,
                                                 float* __restrict__ sdst) {
    int wid = (blockIdx.x * 256 + threadIdx.x) >> 6;
    int lane = threadIdx.x & 63;
    if (wid >= NN) return;
    float ss[4], sd[4];
#pragma unroll
    for (int h = 0; h < 4; h++) {
        float v = hg[(size_t)wid * 256 + h * 64 + lane];
        float ps = v * a_s[h * 64 + lane];
        float pd = v * a_d[h * 64 + lane];
        for (int off = 32; off >= 1; off >>= 1) {
            ps += __shfl_xor(ps, off, 64);
            pd += __shfl_xor(pd, off, 64);
        }
        ss[h] = ps;
        sd[h] = pd;
    }
    if (lane == 0) {
        *(float4*)(ssrc + (size_t)wid * 4) = make_float4(ss[0], ss[1], ss[2], ss[3]);
        *(float4*)(sdst + (size_t)wid * 4) = make_float4(sd[0], sd[1], sd[2], sd[3]);
    }
}

// ---------------------------------------------------------------------------
// GAT1 aggregation, no max-subtraction (scores bounded: |e| < ~4, exp safe).
// One wave/node. Score phase: lane j computes p[4] for edge j0+j. Gather
// phase (uniform flow, shfl sources active): all 64 lanes consume each edge;
// lane covers channels lane*4..+3 (head hh = lane>>4).
// ---------------------------------------------------------------------------
__global__ __launch_bounds__(256) void gat1_agg(const float* __restrict__ hg,
                                                const int* __restrict__ rs,
                                                const int* __restrict__ col,
                                                const float* __restrict__ ssrc,
                                                const float* __restrict__ sdst,
                                                const float* __restrict__ b,
                                                float* __restrict__ out) {
    int wid = (blockIdx.x * 256 + threadIdx.x) >> 6;
    int lane = threadIdx.x & 63;
    if (wid >= NN) return;
    int hh = lane >> 4;
    float4 sd4 = *(const float4*)(sdst + (size_t)wid * 4);
    float sdv[4] = {sd4.x, sd4.y, sd4.z, sd4.w};

    // self-loop p
    float4 sf4 = *(const float4*)(ssrc + (size_t)wid * 4);
    float sfv[4] = {sf4.x, sf4.y, sf4.z, sf4.w};
    float psf[4];
#pragma unroll
    for (int h = 0; h < 4; h++) {
        float e = sfv[h] + sdv[h];
        e = (e >= 0.f) ? e : 0.2f * e;
        psf[h] = __expf(e);
    }
    float pse = (hh & 2) ? ((hh & 1) ? psf[3] : psf[2]) : ((hh & 1) ? psf[1] : psf[0]);
    float4 hvs = *(const float4*)(hg + (size_t)wid * 256 + lane * 4);
    float4 acc;
    acc.x = hvs.x * pse; acc.y = hvs.y * pse; acc.z = hvs.z * pse; acc.w = hvs.w * pse;

    float lsum[4] = {0.f, 0.f, 0.f, 0.f};
    int beg = rs[wid], end = rs[wid + 1];
    for (int j0 = beg; j0 < end; j0 += 64) {
        int cnt = min(64, end - j0);
        int sreg = 0;
        float pv[4] = {0.f, 0.f, 0.f, 0.f};
        if (lane < cnt) {
            sreg = col[j0 + lane];
            float4 sv = *(const float4*)(ssrc + (size_t)sreg * 4);
            float svv[4] = {sv.x, sv.y, sv.z, sv.w};
#pragma unroll
            for (int h = 0; h < 4; h++) {
                float e = svv[h] + sdv[h];
                e = (e >= 0.f) ? e : 0.2f * e;
                pv[h] = __expf(e);
                lsum[h] += pv[h];
            }
        }
        for (int e = 0; e < cnt; e++) {
            int s = __shfl(sreg, e, 64);
            float p0 = __shfl(pv[0], e, 64);
            float p1 = __shfl(pv[1], e, 64);
            float p2 = __shfl(pv[2], e, 64);
            float p3 = __shfl(pv[3], e, 64);
            float p = (hh & 2) ? ((hh & 1) ? p3 : p2) : ((hh & 1) ? p1 : p0);
            float4 hv = *(const float4*)(hg + (size_t)s * 256 + lane * 4);
            acc.x += hv.x * p; acc.y += hv.y * p; acc.z += hv.z * p; acc.w += hv.w * p;
        }
    }
    // reduce lsum across lanes (wave-uniform flow)
#pragma unroll
    for (int h = 0; h < 4; h++) {
        float v = lsum[h];
        for (int off = 32; off >= 1; off >>= 1) v += __shfl_xor(v, off, 64);
        lsum[h] = v + psf[h];
    }
    float lt = (hh & 2) ? ((hh & 1) ? lsum[3] : lsum[2]) : ((hh & 1) ? lsum[1] : lsum[0]);
    float li = 1.0f / lt;
    float4 bv = *(const float4*)(b + lane * 4);
    float4 o;
    o.x = fmaxf(acc.x * li + bv.x, 0.f);
    o.y = fmaxf(acc.y * li + bv.y, 0.f);
    o.z = fmaxf(acc.z * li + bv.z, 0.f);
    o.w = fmaxf(acc.w * li + bv.w, 0.f);
    *(float4*)(out + (size_t)wid * 256 + lane * 4) = o;
}

// ---------------------------------------------------------------------------
// GAT layer 2 (heads=1, C=16)
// ---------------------------------------------------------------------------
__global__ __launch_bounds__(256) void s2_kernel(const float* __restrict__ hg,
                                                 const float* __restrict__ a_s,
                                                 const float* __restrict__ a_d,
                                                 float* __restrict__ ssrc,
                                                 float* __restrict__ sdst) {
    int t = blockIdx.x * 256 + threadIdx.x;
    int node = t >> 4;
    int c = t & 15;
    if (node >= NN) return;
    float v = hg[(size_t)node * 16 + c];
    float ps = v * a_s[c];
    float pd = v * a_d[c];
    for (int off = 8; off >= 1; off >>= 1) {
        ps += __shfl_xor(ps, off, 16);
        pd += __shfl_xor(pd, off, 16);
    }
    if (c == 0) {
        ssrc[node] = ps;
        sdst[node] = pd;
    }
}

__global__ __launch_bounds__(256) void gat2_agg(const float* __restrict__ hg,
                                                const int* __restrict__ rs,
                                                const int* __restrict__ col,
                                                const float* __restrict__ ssrc,
                                                const float* __restrict__ sdst,
                                                const float* __restrict__ b,
                                                float* __restrict__ out) {
    int t = blockIdx.x * 256 + threadIdx.x;
    int node = t >> 4;
    int c = t & 15;
    if (node >= NN) return;
    float sd = sdst[node];
    float es = ssrc[node] + sd;
    es = (es >= 0.f) ? es : 0.2f * es;
    float psf = __expf(es);
    float acc = hg[(size_t)node * 16 + c] * psf;
    float lp = 0.f;
    int beg = rs[node], end = rs[node + 1];
    for (int j0 = beg; j0 < end; j0 += 16) {
        int cnt = min(16, end - j0);
        int sreg = 0;
        float pr = 0.f;
        if (c < cnt) {
            sreg = col[j0 + c];
            float e = ssrc[sreg] + sd;
            e = (e >= 0.f) ? e : 0.2f * e;
            pr = __expf(e);
            lp += pr;
        }
        for (int e = 0; e < cnt; e++) {
            int s = __shfl(sreg, e, 16);
            float p = __shfl(pr, e, 16);
            acc += hg[(size_t)s * 16 + c] * p;
        }
    }
    for (int off = 8; off >= 1; off >>= 1) lp += __shfl_xor(lp, off, 16);
    float l = lp + psf;
    out[(size_t)node * 32 + 16 + c] = acc / l + b[c];
}

// ---------------------------------------------------------------------------
// Launch
// ---------------------------------------------------------------------------
extern "C" void kernel_launch(void* const* d_in, const int* in_sizes, int n_in,
                              void* d_out, int out_size, void* d_ws, size_t ws_size,
                              hipStream_t stream) {
    const float* x      = (const float*)d_in[0];
    const int*   ei     = (const int*)d_in[1];
    const float* Wg1    = (const float*)d_in[2];
    const float* bg1    = (const float*)d_in[3];
    const float* Wg2    = (const float*)d_in[4];
    const float* bg2    = (const float*)d_in[5];
    const float* Wgat1  = (const float*)d_in[6];
    const float* a_src1 = (const float*)d_in[7];
    const float* a_dst1 = (const float*)d_in[8];
    const float* bgat1  = (const float*)d_in[9];
    const float* Wgat2  = (const float*)d_in[10];
    const float* a_src2 = (const float*)d_in[11];
    const float* a_dst2 = (const float*)d_in[12];
    const float* bgat2  = (const float*)d_in[13];
    float* out = (float*)d_out;

    const int* e_src = ei;
    const int* e_dst = ei + EE;

    float* wsf = (float*)d_ws;
    size_t o = 0;
    float* dinv    = wsf + o; o += NN;
    float* ssrc1   = wsf + o; o += (size_t)NN * 4;
    float* sdst1   = wsf + o; o += (size_t)NN * 4;
    float* buf64a  = wsf + o; o += (size_t)NN * 64;
    float* buf64b  = wsf + o; o += (size_t)NN * 64;
    float* buf256a = wsf + o; o += (size_t)NN * 256;
    float* buf256b = wsf + o; o += (size_t)NN * 256;
    int* cnt      = (int*)(wsf + o); o += NN;
    int* rowstart = (int*)(wsf + o); o += NN + 1;
    int* cursor   = (int*)(wsf + o); o += NN;
    int* colarr   = (int*)(wsf + o); o += EE;

    float* h1     = buf64a;   // pre-scaled by dinv
    float* xg1    = buf64b;
    float* h2     = buf64a;   // pre-scaled by dinv
    float* hgat   = buf256a;
    float* xg_at1 = buf256b;
    float* h2g    = buf256a;
    float* s2src  = buf256a + (size_t)NN * 16;
    float* s2dst  = s2src + NN;

    const int TB = 256;
    // CSR build
    k_zero_int<<<(NN + TB - 1) / TB, TB, 0, stream>>>(cnt, NN);
    k_count<<<(EE + TB - 1) / TB, TB, 0, stream>>>(e_dst, cnt, EE);
    k_scan<<<1, 1024, 0, stream>>>(cnt, rowstart, cursor, dinv, NN);
    k_fill<<<(EE + TB - 1) / TB, TB, 0, stream>>>(e_src, e_dst, cursor, colarr, EE);

    // GCN path (h pre-scaled by dinv in GEMM epilogues)
    gemm64<FF><<<dim3((NN + 63) / 64, 1), TB, 0, stream>>>(x, Wg1, h1, NN, HH, dinv);
    gcn1_agg<<<(NN * 64 + TB - 1) / TB, TB, 0, stream>>>(h1, rowstart, colarr, dinv, bg1, xg1);
    gemm_n16<HH><<<(NN * 16 + TB - 1) / TB, TB, 0, stream>>>(xg1, Wg2, h2, NN, dinv);
    gcn2_agg<<<(NN * 16 + TB - 1) / TB, TB, 0, stream>>>(h2, rowstart, colarr, dinv, bg2, out);

    // GAT path
    gemm64<FF><<<dim3((NN + 63) / 64, 4), TB, 0, stream>>>(x, Wgat1, hgat, NN, NHEADS * HH, nullptr);
    s1_kernel<<<(NN * 64 + TB - 1) / TB, TB, 0, stream>>>(hgat, a_src1, a_dst1, ssrc1, sdst1);
    gat1_agg<<<(NN * 64 + TB - 1) / TB, TB, 0, stream>>>(hgat, rowstart, colarr, ssrc1, sdst1, bgat1, xg_at1);
    gemm_n16<NHEADS * HH><<<(NN * 16 + TB - 1) / TB, TB, 0, stream>>>(xg_at1, Wgat2, h2g, NN, nullptr);
    s2_kernel<<<(NN * 16 + TB - 1) / TB, TB, 0, stream>>>(h2g, a_src2, a_dst2, s2src, s2dst);
    gat2_agg<<<(NN * 16 + TB - 1) / TB, TB, 0, stream>>>(h2g, rowstart, colarr, s2src, s2dst, bgat2, out);
}

// Round 4
// 615.635 us; speedup vs baseline: 1.3260x; 1.1950x over previous
//
#include <hip/hip_runtime.h>
#include <math.h>

#define NN     50000
#define FF     256
#define HH     64
#define NHEADS 4
#define EE     800000
#define OUTD   16

typedef __attribute__((ext_vector_type(8))) short short8;
typedef __attribute__((ext_vector_type(4))) float f32x4;

__device__ inline unsigned short f2bf(float f) {
    unsigned u = __builtin_bit_cast(unsigned, f);
    unsigned r = (u + 0x7fff + ((u >> 16) & 1)) >> 16;
    return (unsigned short)r;
}
__device__ inline float bf2f(unsigned short s) {
    unsigned u = ((unsigned)s) << 16;
    return __builtin_bit_cast(float, u);
}

// ---------------------------------------------------------------------------
// CSR build
// ---------------------------------------------------------------------------
__global__ void k_zero_int(int* __restrict__ p, int n) {
    int i = blockIdx.x * blockDim.x + threadIdx.x;
    if (i < n) p[i] = 0;
}

__global__ void k_count(const int* __restrict__ dst, int* __restrict__ cnt, int e) {
    int i = blockIdx.x * blockDim.x + threadIdx.x;
    if (i < e) atomicAdd(&cnt[dst[i]], 1);
}

__global__ __launch_bounds__(1024) void k_scan(const int* __restrict__ cnt,
                                               int* __restrict__ row_start,
                                               int* __restrict__ cursor,
                                               float* __restrict__ dinv, int n) {
    __shared__ int part[1024];
    int tid = threadIdx.x;
    int chunk = (n + 1023) >> 10;
    int beg = tid * chunk;
    int end = min(beg + chunk, n);
    int s = 0;
    for (int i = beg; i < end; i++) s += cnt[i];
    part[tid] = s;
    __syncthreads();
    for (int off = 1; off < 1024; off <<= 1) {
        int v = part[tid];
        int add = (tid >= off) ? part[tid - off] : 0;
        __syncthreads();
        part[tid] = v + add;
        __syncthreads();
    }
    int base = (tid > 0) ? part[tid - 1] : 0;
    for (int i = beg; i < end; i++) {
        int c = cnt[i];
        row_start[i] = base;
        cursor[i] = base;
        dinv[i] = rsqrtf((float)(c + 1));
        base += c;
    }
    if (tid == 0) row_start[n] = part[1023];
}

__global__ void k_fill(const int* __restrict__ src, const int* __restrict__ dst,
                       int* __restrict__ cursor, int* __restrict__ col, int e) {
    int i = blockIdx.x * blockDim.x + threadIdx.x;
    if (i < e) {
        int d = dst[i];
        int pos = atomicAdd(&cursor[d], 1);
        col[pos] = src[i];
    }
}

// ---------------------------------------------------------------------------
// Pack W (K=256 x NC=NT*16, row-major fp32) into MFMA B-fragment layout,
// split hi/lo bf16 (bf16x2 compensation). Fragment: for k-block kb, tile t,
// lane L: B[kb*32 + (L>>4)*8 + j][t*16 + (L&15)], j=0..7 contiguous.
// ---------------------------------------------------------------------------
template <int NT>
__global__ void k_pack_w(const float* __restrict__ W,
                         unsigned short* __restrict__ bhi,
                         unsigned short* __restrict__ blo) {
    int t_ = blockIdx.x * blockDim.x + threadIdx.x;
    const int total = 8 * NT * 64;
    if (t_ >= total) return;
    int lane = t_ & 63;
    int tile = (t_ >> 6) % NT;
    int kb = (t_ >> 6) / NT;
    int q = lane >> 4, c = lane & 15;
    const int NC = NT * 16;
    size_t off = ((size_t)(kb * NT + tile) * 64 + lane) * 8;
#pragma unroll
    for (int j = 0; j < 8; j++) {
        float w = W[(size_t)(kb * 32 + q * 8 + j) * NC + tile * 16 + c];
        unsigned short h = f2bf(w);
        bhi[off + j] = h;
        blo[off + j] = f2bf(w - bf2f(h));
    }
}

// ---------------------------------------------------------------------------
// MFMA GEMM: C_bf16[M, NT*16] = A_f32[M,256] @ W (packed hi/lo), optional
// per-row scale. Block = 256 thr = 4 waves, 64 rows/block, wave w -> 16 rows.
// bf16x2: acc += Ahi*Bhi + Alo*Bhi + Ahi*Blo  (fp32-equivalent accuracy).
// A-frag: lane holds A[row0 + (lane&15)][k0 + (lane>>4)*8 + j].
// C/D: col = lane&15, row = (lane>>4)*4 + reg   [HW-verified layouts].
// ---------------------------------------------------------------------------
template <int NT, bool SCALE>
__global__ __launch_bounds__(256) void mfma_gemm(const float* __restrict__ A,
                                                 const unsigned short* __restrict__ Bhi,
                                                 const unsigned short* __restrict__ Blo,
                                                 unsigned short* __restrict__ Cbf,
                                                 const float* __restrict__ rowscale,
                                                 int M) {
    const int K = 256, NC = NT * 16;
    int tid = threadIdx.x;
    int w = tid >> 6, lane = tid & 63, q = lane >> 4, c = lane & 15;
    int row_base = blockIdx.x * 64 + w * 16;
    int ar = min(row_base + c, M - 1);   // clamp; garbage rows never stored
    const float* ap = A + (size_t)ar * K + q * 8;

    f32x4 acc[NT];
#pragma unroll
    for (int t = 0; t < NT; t++) acc[t] = (f32x4){0.f, 0.f, 0.f, 0.f};

    for (int kb = 0; kb < 8; kb++) {
        float av[8];
        *(float4*)(av)     = *(const float4*)(ap + kb * 32);
        *(float4*)(av + 4) = *(const float4*)(ap + kb * 32 + 4);
        short8 ahi, alo;
#pragma unroll
        for (int j = 0; j < 8; j++) {
            unsigned short h = f2bf(av[j]);
            ahi[j] = (short)h;
            alo[j] = (short)f2bf(av[j] - bf2f(h));
        }
#pragma unroll
        for (int t = 0; t < NT; t++) {
            size_t bo = ((size_t)(kb * NT + t) * 64 + lane) * 8;
            short8 bhi = *(const short8*)(Bhi + bo);
            short8 blo = *(const short8*)(Blo + bo);
            acc[t] = __builtin_amdgcn_mfma_f32_16x16x32_bf16(ahi, bhi, acc[t], 0, 0, 0);
            acc[t] = __builtin_amdgcn_mfma_f32_16x16x32_bf16(alo, bhi, acc[t], 0, 0, 0);
            acc[t] = __builtin_amdgcn_mfma_f32_16x16x32_bf16(ahi, blo, acc[t], 0, 0, 0);
        }
    }
#pragma unroll
    for (int i = 0; i < 4; i++) {
        int r = row_base + q * 4 + i;
        if (r < M) {
            float sc = SCALE ? rowscale[r] : 1.0f;
#pragma unroll
            for (int t = 0; t < NT; t++)
                Cbf[(size_t)r * NC + t * 16 + c] = f2bf(acc[t][i] * sc);
        }
    }
}

// GEMM KOUT=16 (fp32 in/out), optional per-row output scale.
template <int KIN>
__global__ __launch_bounds__(256) void gemm_n16(const float* __restrict__ A,
                                                const float* __restrict__ W,
                                                float* __restrict__ C, int M,
                                                const float* __restrict__ rowscale) {
    __shared__ float Ws[KIN * 16];
    for (int i = threadIdx.x; i < KIN * 16; i += 256) Ws[i] = W[i];
    __syncthreads();
    int t = blockIdx.x * 256 + threadIdx.x;
    int row = t >> 4;
    int c = t & 15;
    if (row >= M) return;
    const float* a = A + (size_t)row * KIN;
    float acc = 0.f;
#pragma unroll 8
    for (int k = 0; k < KIN; k += 4) {
        float4 av = *(const float4*)(a + k);
        acc += av.x * Ws[(k + 0) * 16 + c];
        acc += av.y * Ws[(k + 1) * 16 + c];
        acc += av.z * Ws[(k + 2) * 16 + c];
        acc += av.w * Ws[(k + 3) * 16 + c];
    }
    float sc = rowscale ? rowscale[row] : 1.0f;
    C[(size_t)row * 16 + c] = acc * sc;
}

// ---------------------------------------------------------------------------
// GCN1 aggregation, h1 stored bf16 (64 ch = 128 B/row), pre-scaled by dinv.
// One wave/node; 4 groups of 16 lanes process 4 edges in parallel.
// __shfl unconditional (round-2 lesson: inactive-source bpermute undefined).
// ---------------------------------------------------------------------------
__global__ __launch_bounds__(256) void gcn1_agg(const unsigned short* __restrict__ h,
                                                const int* __restrict__ rs,
                                                const int* __restrict__ col,
                                                const float* __restrict__ dinv,
                                                const float* __restrict__ b,
                                                float* __restrict__ out) {
    int wid = (blockIdx.x * 256 + threadIdx.x) >> 6;
    int lane = threadIdx.x & 63;
    if (wid >= NN) return;
    int g = lane >> 4;
    int cidx = (lane & 15) * 4;
    float di = dinv[wid];
    int beg = rs[wid], end = rs[wid + 1];
    float4 acc = make_float4(0.f, 0.f, 0.f, 0.f);

    for (int j0 = beg; j0 < end; j0 += 64) {
        int cnt = min(64, end - j0);
        int sreg = 0;
        if (lane < cnt) sreg = col[j0 + lane];
        for (int e = 0; e < cnt; e += 4) {
            int myE = e + g;
            int s = __shfl(sreg, myE, 64);
            if (myE < cnt) {
                ushort4 v = *(const ushort4*)(h + (size_t)s * HH + cidx);
                acc.x += bf2f(v.x); acc.y += bf2f(v.y);
                acc.z += bf2f(v.z); acc.w += bf2f(v.w);
            }
        }
    }
#pragma unroll
    for (int off = 16; off <= 32; off <<= 1) {
        acc.x += __shfl_xor(acc.x, off, 64);
        acc.y += __shfl_xor(acc.y, off, 64);
        acc.z += __shfl_xor(acc.z, off, 64);
        acc.w += __shfl_xor(acc.w, off, 64);
    }
    if (g == 0) {
        ushort4 sv = *(const ushort4*)(h + (size_t)wid * HH + cidx);
        float4 bv = *(const float4*)(b + cidx);
        float4 o;
        o.x = fmaxf((acc.x + bf2f(sv.x)) * di + bv.x, 0.f);
        o.y = fmaxf((acc.y + bf2f(sv.y)) * di + bv.y, 0.f);
        o.z = fmaxf((acc.z + bf2f(sv.z)) * di + bv.z, 0.f);
        o.w = fmaxf((acc.w + bf2f(sv.w)) * di + bv.w, 0.f);
        *(float4*)(out + (size_t)wid * HH + cidx) = o;
    }
}

// ---------------------------------------------------------------------------
// GCN2 aggregation (fp32, 16 lanes/node) — unchanged.
// ---------------------------------------------------------------------------
__global__ __launch_bounds__(256) void gcn2_agg(const float* __restrict__ h,
                                                const int* __restrict__ rs,
                                                const int* __restrict__ col,
                                                const float* __restrict__ dinv,
                                                const float* __restrict__ b,
                                                float* __restrict__ out) {
    int t = blockIdx.x * 256 + threadIdx.x;
    int node = t >> 4;
    int c = t & 15;
    if (node >= NN) return;
    float di = dinv[node];
    int beg = rs[node], end = rs[node + 1];
    float acc = h[(size_t)node * 16 + c];
    for (int j0 = beg; j0 < end; j0 += 16) {
        int cnt = min(16, end - j0);
        int sreg = 0;
        if (c < cnt) sreg = col[j0 + c];
        for (int e = 0; e < cnt; e++) {
            int s = __shfl(sreg, e, 16);
            acc += h[(size_t)s * 16 + c];
        }
    }
    out[(size_t)node * 32 + c] = acc * di + b[c];
}

// ---------------------------------------------------------------------------
// GAT layer 1 scores (hgat now bf16)
// ---------------------------------------------------------------------------
__global__ __launch_bounds__(256) void s1_kernel(const unsigned short* __restrict__ hg,
                                                 const float* __restrict__ a_s,
                                                 const float* __restrict__ a_d,
                                                 float* __restrict__ ssrc,
                                                 float* __restrict__ sdst) {
    int wid = (blockIdx.x * 256 + threadIdx.x) >> 6;
    int lane = threadIdx.x & 63;
    if (wid >= NN) return;
    float ss[4], sd[4];
#pragma unroll
    for (int h = 0; h < 4; h++) {
        float v = bf2f(hg[(size_t)wid * 256 + h * 64 + lane]);
        float ps = v * a_s[h * 64 + lane];
        float pd = v * a_d[h * 64 + lane];
        for (int off = 32; off >= 1; off >>= 1) {
            ps += __shfl_xor(ps, off, 64);
            pd += __shfl_xor(pd, off, 64);
        }
        ss[h] = ps;
        sd[h] = pd;
    }
    if (lane == 0) {
        *(float4*)(ssrc + (size_t)wid * 4) = make_float4(ss[0], ss[1], ss[2], ss[3]);
        *(float4*)(sdst + (size_t)wid * 4) = make_float4(sd[0], sd[1], sd[2], sd[3]);
    }
}

// ---------------------------------------------------------------------------
// GAT1 aggregation: bf16 gather (512 B/row), no max-subtraction (|e|<~4).
// ---------------------------------------------------------------------------
__global__ __launch_bounds__(256) void gat1_agg(const unsigned short* __restrict__ hg,
                                                const int* __restrict__ rs,
                                                const int* __restrict__ col,
                                                const float* __restrict__ ssrc,
                                                const float* __restrict__ sdst,
                                                const float* __restrict__ b,
                                                float* __restrict__ out) {
    int wid = (blockIdx.x * 256 + threadIdx.x) >> 6;
    int lane = threadIdx.x & 63;
    if (wid >= NN) return;
    int hh = lane >> 4;
    float4 sd4 = *(const float4*)(sdst + (size_t)wid * 4);
    float sdv[4] = {sd4.x, sd4.y, sd4.z, sd4.w};

    float4 sf4 = *(const float4*)(ssrc + (size_t)wid * 4);
    float sfv[4] = {sf4.x, sf4.y, sf4.z, sf4.w};
    float psf[4];
#pragma unroll
    for (int h = 0; h < 4; h++) {
        float e = sfv[h] + sdv[h];
        e = (e >= 0.f) ? e : 0.2f * e;
        psf[h] = __expf(e);
    }
    float pse = (hh & 2) ? ((hh & 1) ? psf[3] : psf[2]) : ((hh & 1) ? psf[1] : psf[0]);
    ushort4 hvs = *(const ushort4*)(hg + (size_t)wid * 256 + lane * 4);
    float4 acc;
    acc.x = bf2f(hvs.x) * pse; acc.y = bf2f(hvs.y) * pse;
    acc.z = bf2f(hvs.z) * pse; acc.w = bf2f(hvs.w) * pse;

    float lsum[4] = {0.f, 0.f, 0.f, 0.f};
    int beg = rs[wid], end = rs[wid + 1];
    for (int j0 = beg; j0 < end; j0 += 64) {
        int cnt = min(64, end - j0);
        int sreg = 0;
        float pv[4] = {0.f, 0.f, 0.f, 0.f};
        if (lane < cnt) {
            sreg = col[j0 + lane];
            float4 sv = *(const float4*)(ssrc + (size_t)sreg * 4);
            float svv[4] = {sv.x, sv.y, sv.z, sv.w};
#pragma unroll
            for (int h = 0; h < 4; h++) {
                float e = svv[h] + sdv[h];
                e = (e >= 0.f) ? e : 0.2f * e;
                pv[h] = __expf(e);
                lsum[h] += pv[h];
            }
        }
        for (int e = 0; e < cnt; e++) {
            int s = __shfl(sreg, e, 64);
            float p0 = __shfl(pv[0], e, 64);
            float p1 = __shfl(pv[1], e, 64);
            float p2 = __shfl(pv[2], e, 64);
            float p3 = __shfl(pv[3], e, 64);
            float p = (hh & 2) ? ((hh & 1) ? p3 : p2) : ((hh & 1) ? p1 : p0);
            ushort4 hv = *(const ushort4*)(hg + (size_t)s * 256 + lane * 4);
            acc.x += bf2f(hv.x) * p; acc.y += bf2f(hv.y) * p;
            acc.z += bf2f(hv.z) * p; acc.w += bf2f(hv.w) * p;
        }
    }
#pragma unroll
    for (int h = 0; h < 4; h++) {
        float v = lsum[h];
        for (int off = 32; off >= 1; off >>= 1) v += __shfl_xor(v, off, 64);
        lsum[h] = v + psf[h];
    }
    float lt = (hh & 2) ? ((hh & 1) ? lsum[3] : lsum[2]) : ((hh & 1) ? lsum[1] : lsum[0]);
    float li = 1.0f / lt;
    float4 bv = *(const float4*)(b + lane * 4);
    float4 o;
    o.x = fmaxf(acc.x * li + bv.x, 0.f);
    o.y = fmaxf(acc.y * li + bv.y, 0.f);
    o.z = fmaxf(acc.z * li + bv.z, 0.f);
    o.w = fmaxf(acc.w * li + bv.w, 0.f);
    *(float4*)(out + (size_t)wid * 256 + lane * 4) = o;
}

// ---------------------------------------------------------------------------
// GAT layer 2 (heads=1, C=16) — unchanged fp32.
// ---------------------------------------------------------------------------
__global__ __launch_bounds__(256) void s2_kernel(const float* __restrict__ hg,
                                                 const float* __restrict__ a_s,
                                                 const float* __restrict__ a_d,
                                                 float* __restrict__ ssrc,
                                                 float* __restrict__ sdst) {
    int t = blockIdx.x * 256 + threadIdx.x;
    int node = t >> 4;
    int c = t & 15;
    if (node >= NN) return;
    float v = hg[(size_t)node * 16 + c];
    float ps = v * a_s[c];
    float pd = v * a_d[c];
    for (int off = 8; off >= 1; off >>= 1) {
        ps += __shfl_xor(ps, off, 16);
        pd += __shfl_xor(pd, off, 16);
    }
    if (c == 0) {
        ssrc[node] = ps;
        sdst[node] = pd;
    }
}

__global__ __launch_bounds__(256) void gat2_agg(const float* __restrict__ hg,
                                                const int* __restrict__ rs,
                                                const int* __restrict__ col,
                                                const float* __restrict__ ssrc,
                                                const float* __restrict__ sdst,
                                                const float* __restrict__ b,
                                                float* __restrict__ out) {
    int t = blockIdx.x * 256 + threadIdx.x;
    int node = t >> 4;
    int c = t & 15;
    if (node >= NN) return;
    float sd = sdst[node];
    float es = ssrc[node] + sd;
    es = (es >= 0.f) ? es : 0.2f * es;
    float psf = __expf(es);
    float acc = hg[(size_t)node * 16 + c] * psf;
    float lp = 0.f;
    int beg = rs[node], end = rs[node + 1];
    for (int j0 = beg; j0 < end; j0 += 16) {
        int cnt = min(16, end - j0);
        int sreg = 0;
        float pr = 0.f;
        if (c < cnt) {
            sreg = col[j0 + c];
            float e = ssrc[sreg] + sd;
            e = (e >= 0.f) ? e : 0.2f * e;
            pr = __expf(e);
            lp += pr;
        }
        for (int e = 0; e < cnt; e++) {
            int s = __shfl(sreg, e, 16);
            float p = __shfl(pr, e, 16);
            acc += hg[(size_t)s * 16 + c] * p;
        }
    }
    for (int off = 8; off >= 1; off >>= 1) lp += __shfl_xor(lp, off, 16);
    float l = lp + psf;
    out[(size_t)node * 32 + 16 + c] = acc / l + b[c];
}

// ---------------------------------------------------------------------------
// Launch
// ---------------------------------------------------------------------------
extern "C" void kernel_launch(void* const* d_in, const int* in_sizes, int n_in,
                              void* d_out, int out_size, void* d_ws, size_t ws_size,
                              hipStream_t stream) {
    const float* x      = (const float*)d_in[0];
    const int*   ei     = (const int*)d_in[1];
    const float* Wg1    = (const float*)d_in[2];
    const float* bg1    = (const float*)d_in[3];
    const float* Wg2    = (const float*)d_in[4];
    const float* bg2    = (const float*)d_in[5];
    const float* Wgat1  = (const float*)d_in[6];
    const float* a_src1 = (const float*)d_in[7];
    const float* a_dst1 = (const float*)d_in[8];
    const float* bgat1  = (const float*)d_in[9];
    const float* Wgat2  = (const float*)d_in[10];
    const float* a_src2 = (const float*)d_in[11];
    const float* a_dst2 = (const float*)d_in[12];
    const float* bgat2  = (const float*)d_in[13];
    float* out = (float*)d_out;

    const int* e_src = ei;
    const int* e_dst = ei + EE;

    char* wsb = (char*)d_ws;
    size_t o = 0;
    auto alloc = [&](size_t bytes) -> void* {
        void* p = wsb + o;
        o += (bytes + 255) & ~(size_t)255;
        return p;
    };
    float* dinv            = (float*)alloc(NN * 4);
    float* ssrc1           = (float*)alloc((size_t)NN * 16);
    float* sdst1           = (float*)alloc((size_t)NN * 16);
    unsigned short* h1b    = (unsigned short*)alloc((size_t)NN * HH * 2);
    float* xg1             = (float*)alloc((size_t)NN * HH * 4);
    float* h2              = (float*)alloc((size_t)NN * 16 * 4);
    unsigned short* hgb    = (unsigned short*)alloc((size_t)NN * 256 * 2);
    float* xgat1           = (float*)alloc((size_t)NN * 256 * 4);
    float* h2g             = (float*)alloc((size_t)NN * 16 * 4);
    float* s2src           = (float*)alloc(NN * 4);
    float* s2dst           = (float*)alloc(NN * 4);
    unsigned short* bhi1   = (unsigned short*)alloc(256 * 64 * 2);
    unsigned short* blo1   = (unsigned short*)alloc(256 * 64 * 2);
    unsigned short* bhi2   = (unsigned short*)alloc(256 * 256 * 2);
    unsigned short* blo2   = (unsigned short*)alloc(256 * 256 * 2);
    int* cnt               = (int*)alloc(NN * 4);
    int* rowstart          = (int*)alloc((NN + 1) * 4);
    int* cursor            = (int*)alloc(NN * 4);
    int* colarr            = (int*)alloc((size_t)EE * 4);

    const int TB = 256;
    // CSR build + weight packing (independent)
    k_zero_int<<<(NN + TB - 1) / TB, TB, 0, stream>>>(cnt, NN);
    k_count<<<(EE + TB - 1) / TB, TB, 0, stream>>>(e_dst, cnt, EE);
    k_scan<<<1, 1024, 0, stream>>>(cnt, rowstart, cursor, dinv, NN);
    k_fill<<<(EE + TB - 1) / TB, TB, 0, stream>>>(e_src, e_dst, cursor, colarr, EE);
    k_pack_w<4><<<(8 * 4 * 64 + TB - 1) / TB, TB, 0, stream>>>(Wg1, bhi1, blo1);
    k_pack_w<16><<<(8 * 16 * 64 + TB - 1) / TB, TB, 0, stream>>>(Wgat1, bhi2, blo2);

    const int GB = (NN + 63) / 64;  // 782 row-blocks
    // GCN path (h1 bf16, pre-scaled by dinv)
    mfma_gemm<4, true><<<GB, TB, 0, stream>>>(x, bhi1, blo1, h1b, dinv, NN);
    gcn1_agg<<<(NN * 64 + TB - 1) / TB, TB, 0, stream>>>(h1b, rowstart, colarr, dinv, bg1, xg1);
    gemm_n16<HH><<<(NN * 16 + TB - 1) / TB, TB, 0, stream>>>(xg1, Wg2, h2, NN, dinv);
    gcn2_agg<<<(NN * 16 + TB - 1) / TB, TB, 0, stream>>>(h2, rowstart, colarr, dinv, bg2, out);

    // GAT path (hgat bf16)
    mfma_gemm<16, false><<<GB, TB, 0, stream>>>(x, bhi2, blo2, hgb, nullptr, NN);
    s1_kernel<<<(NN * 64 + TB - 1) / TB, TB, 0, stream>>>(hgb, a_src1, a_dst1, ssrc1, sdst1);
    gat1_agg<<<(NN * 64 + TB - 1) / TB, TB, 0, stream>>>(hgb, rowstart, colarr, ssrc1, sdst1, bgat1, xgat1);
    gemm_n16<NHEADS * HH><<<(NN * 16 + TB - 1) / TB, TB, 0, stream>>>(xgat1, Wgat2, h2g, NN, nullptr);
    s2_kernel<<<(NN * 16 + TB - 1) / TB, TB, 0, stream>>>(h2g, a_src2, a_dst2, s2src, s2dst);
    gat2_agg<<<(NN * 16 + TB - 1) / TB, TB, 0, stream>>>(h2g, rowstart, colarr, s2src, s2dst, bgat2, out);
}

// Round 5
// 495.350 us; speedup vs baseline: 1.6480x; 1.2428x over previous
//
#include <hip/hip_runtime.h>
#include <math.h>

#define NN     50000
#define FF     256
#define HH     64
#define NHEADS 4
#define EE     800000
#define OUTD   16

typedef __attribute__((ext_vector_type(8))) short short8;
typedef __attribute__((ext_vector_type(4))) float f32x4;

__device__ inline unsigned short f2bf(float f) {
    unsigned u = __builtin_bit_cast(unsigned, f);
    unsigned r = (u + 0x7fff + ((u >> 16) & 1)) >> 16;
    return (unsigned short)r;
}
__device__ inline float bf2f(unsigned short s) {
    unsigned u = ((unsigned)s) << 16;
    return __builtin_bit_cast(float, u);
}

// ---------------------------------------------------------------------------
// CSR build. Scan is 3-phase hierarchical (round-4 lesson: the single-block
// 1024-thread scan was 136 us at 0.14% occupancy — latency-serialized).
// ---------------------------------------------------------------------------
__global__ void k_zero_int(int* __restrict__ p, int n) {
    int i = blockIdx.x * blockDim.x + threadIdx.x;
    if (i < n) p[i] = 0;
}

__global__ void k_count(const int* __restrict__ dst, int* __restrict__ cnt, int e) {
    int i = blockIdx.x * blockDim.x + threadIdx.x;
    if (i < e) atomicAdd(&cnt[dst[i]], 1);
}

// Phase A: per-block (256-elem) sums.
__global__ __launch_bounds__(256) void k_scan_a(const int* __restrict__ cnt,
                                                int* __restrict__ partial, int n) {
    int i = blockIdx.x * 256 + threadIdx.x;
    int v = (i < n) ? cnt[i] : 0;
#pragma unroll
    for (int off = 32; off >= 1; off >>= 1) v += __shfl_xor(v, off, 64);
    __shared__ int ws[4];
    int wave = threadIdx.x >> 6;
    if ((threadIdx.x & 63) == 0) ws[wave] = v;
    __syncthreads();
    if (threadIdx.x == 0) partial[blockIdx.x] = ws[0] + ws[1] + ws[2] + ws[3];
}

// Phase B: single small block scans the <=256 partials -> exclusive offsets.
__global__ __launch_bounds__(256) void k_scan_b(const int* __restrict__ partial,
                                                int* __restrict__ blockoff,
                                                int* __restrict__ total_out, int nb) {
    __shared__ int arr[256];
    int tid = threadIdx.x;
    arr[tid] = (tid < nb) ? partial[tid] : 0;
    __syncthreads();
#pragma unroll
    for (int off = 1; off < 256; off <<= 1) {
        int v = arr[tid];
        int add = (tid >= off) ? arr[tid - off] : 0;
        __syncthreads();
        arr[tid] = v + add;
        __syncthreads();
    }
    if (tid < nb) blockoff[tid] = arr[tid] - partial[tid];  // exclusive
    if (tid == 0) *total_out = arr[255];
}

// Phase C: block-local exclusive scan + block offset; emit CSR arrays + dinv.
__global__ __launch_bounds__(256) void k_scan_c(const int* __restrict__ cnt,
                                                const int* __restrict__ blockoff,
                                                int* __restrict__ row_start,
                                                int* __restrict__ cursor,
                                                float* __restrict__ dinv, int n) {
    __shared__ int arr[256];
    int tid = threadIdx.x;
    int i = blockIdx.x * 256 + tid;
    int c = (i < n) ? cnt[i] : 0;
    arr[tid] = c;
    __syncthreads();
#pragma unroll
    for (int off = 1; off < 256; off <<= 1) {
        int v = arr[tid];
        int add = (tid >= off) ? arr[tid - off] : 0;
        __syncthreads();
        arr[tid] = v + add;
        __syncthreads();
    }
    if (i < n) {
        int excl = arr[tid] - c + blockoff[blockIdx.x];
        row_start[i] = excl;
        cursor[i] = excl;
        dinv[i] = rsqrtf((float)(c + 1));
    }
}

__global__ void k_fill(const int* __restrict__ src, const int* __restrict__ dst,
                       int* __restrict__ cursor, int* __restrict__ col, int e) {
    int i = blockIdx.x * blockDim.x + threadIdx.x;
    if (i < e) {
        int d = dst[i];
        int pos = atomicAdd(&cursor[d], 1);
        col[pos] = src[i];
    }
}

// ---------------------------------------------------------------------------
// Pack W (K=256 x NC=NT*16, row-major fp32) into MFMA B-fragment layout,
// split hi/lo bf16 (bf16x2 compensation).
// ---------------------------------------------------------------------------
template <int NT>
__global__ void k_pack_w(const float* __restrict__ W,
                         unsigned short* __restrict__ bhi,
                         unsigned short* __restrict__ blo) {
    int t_ = blockIdx.x * blockDim.x + threadIdx.x;
    const int total = 8 * NT * 64;
    if (t_ >= total) return;
    int lane = t_ & 63;
    int tile = (t_ >> 6) % NT;
    int kb = (t_ >> 6) / NT;
    int q = lane >> 4, c = lane & 15;
    const int NC = NT * 16;
    size_t off = ((size_t)(kb * NT + tile) * 64 + lane) * 8;
#pragma unroll
    for (int j = 0; j < 8; j++) {
        float w = W[(size_t)(kb * 32 + q * 8 + j) * NC + tile * 16 + c];
        unsigned short h = f2bf(w);
        bhi[off + j] = h;
        blo[off + j] = f2bf(w - bf2f(h));
    }
}

// ---------------------------------------------------------------------------
// MFMA GEMM: C_bf16[M, NT*16] = A_f32[M,256] @ W (packed hi/lo), optional
// per-row scale. bf16x2: acc += Ahi*Bhi + Alo*Bhi + Ahi*Blo.
// ---------------------------------------------------------------------------
template <int NT, bool SCALE>
__global__ __launch_bounds__(256) void mfma_gemm(const float* __restrict__ A,
                                                 const unsigned short* __restrict__ Bhi,
                                                 const unsigned short* __restrict__ Blo,
                                                 unsigned short* __restrict__ Cbf,
                                                 const float* __restrict__ rowscale,
                                                 int M) {
    const int K = 256, NC = NT * 16;
    int tid = threadIdx.x;
    int w = tid >> 6, lane = tid & 63, q = lane >> 4, c = lane & 15;
    int row_base = blockIdx.x * 64 + w * 16;
    int ar = min(row_base + c, M - 1);
    const float* ap = A + (size_t)ar * K + q * 8;

    f32x4 acc[NT];
#pragma unroll
    for (int t = 0; t < NT; t++) acc[t] = (f32x4){0.f, 0.f, 0.f, 0.f};

    for (int kb = 0; kb < 8; kb++) {
        float av[8];
        *(float4*)(av)     = *(const float4*)(ap + kb * 32);
        *(float4*)(av + 4) = *(const float4*)(ap + kb * 32 + 4);
        short8 ahi, alo;
#pragma unroll
        for (int j = 0; j < 8; j++) {
            unsigned short h = f2bf(av[j]);
            ahi[j] = (short)h;
            alo[j] = (short)f2bf(av[j] - bf2f(h));
        }
#pragma unroll
        for (int t = 0; t < NT; t++) {
            size_t bo = ((size_t)(kb * NT + t) * 64 + lane) * 8;
            short8 bhi = *(const short8*)(Bhi + bo);
            short8 blo = *(const short8*)(Blo + bo);
            acc[t] = __builtin_amdgcn_mfma_f32_16x16x32_bf16(ahi, bhi, acc[t], 0, 0, 0);
            acc[t] = __builtin_amdgcn_mfma_f32_16x16x32_bf16(alo, bhi, acc[t], 0, 0, 0);
            acc[t] = __builtin_amdgcn_mfma_f32_16x16x32_bf16(ahi, blo, acc[t], 0, 0, 0);
        }
    }
#pragma unroll
    for (int i = 0; i < 4; i++) {
        int r = row_base + q * 4 + i;
        if (r < M) {
            float sc = SCALE ? rowscale[r] : 1.0f;
#pragma unroll
            for (int t = 0; t < NT; t++)
                Cbf[(size_t)r * NC + t * 16 + c] = f2bf(acc[t][i] * sc);
        }
    }
}

// GEMM KOUT=16 (fp32 in/out), optional per-row output scale.
template <int KIN>
__global__ __launch_bounds__(256) void gemm_n16(const float* __restrict__ A,
                                                const float* __restrict__ W,
                                                float* __restrict__ C, int M,
                                                const float* __restrict__ rowscale) {
    __shared__ float Ws[KIN * 16];
    for (int i = threadIdx.x; i < KIN * 16; i += 256) Ws[i] = W[i];
    __syncthreads();
    int t = blockIdx.x * 256 + threadIdx.x;
    int row = t >> 4;
    int c = t & 15;
    if (row >= M) return;
    const float* a = A + (size_t)row * KIN;
    float acc = 0.f;
#pragma unroll 8
    for (int k = 0; k < KIN; k += 4) {
        float4 av = *(const float4*)(a + k);
        acc += av.x * Ws[(k + 0) * 16 + c];
        acc += av.y * Ws[(k + 1) * 16 + c];
        acc += av.z * Ws[(k + 2) * 16 + c];
        acc += av.w * Ws[(k + 3) * 16 + c];
    }
    float sc = rowscale ? rowscale[row] : 1.0f;
    C[(size_t)row * 16 + c] = acc * sc;
}

// ---------------------------------------------------------------------------
// GCN1 aggregation, h1 bf16 (128 B/row), pre-scaled by dinv.
// __shfl unconditional (round-2 lesson: inactive-source bpermute undefined).
// ---------------------------------------------------------------------------
__global__ __launch_bounds__(256) void gcn1_agg(const unsigned short* __restrict__ h,
                                                const int* __restrict__ rs,
                                                const int* __restrict__ col,
                                                const float* __restrict__ dinv,
                                                const float* __restrict__ b,
                                                float* __restrict__ out) {
    int wid = (blockIdx.x * 256 + threadIdx.x) >> 6;
    int lane = threadIdx.x & 63;
    if (wid >= NN) return;
    int g = lane >> 4;
    int cidx = (lane & 15) * 4;
    float di = dinv[wid];
    int beg = rs[wid], end = rs[wid + 1];
    float4 acc = make_float4(0.f, 0.f, 0.f, 0.f);

    for (int j0 = beg; j0 < end; j0 += 64) {
        int cnt = min(64, end - j0);
        int sreg = 0;
        if (lane < cnt) sreg = col[j0 + lane];
        for (int e = 0; e < cnt; e += 4) {
            int myE = e + g;
            int s = __shfl(sreg, myE, 64);
            if (myE < cnt) {
                ushort4 v = *(const ushort4*)(h + (size_t)s * HH + cidx);
                acc.x += bf2f(v.x); acc.y += bf2f(v.y);
                acc.z += bf2f(v.z); acc.w += bf2f(v.w);
            }
        }
    }
#pragma unroll
    for (int off = 16; off <= 32; off <<= 1) {
        acc.x += __shfl_xor(acc.x, off, 64);
        acc.y += __shfl_xor(acc.y, off, 64);
        acc.z += __shfl_xor(acc.z, off, 64);
        acc.w += __shfl_xor(acc.w, off, 64);
    }
    if (g == 0) {
        ushort4 sv = *(const ushort4*)(h + (size_t)wid * HH + cidx);
        float4 bv = *(const float4*)(b + cidx);
        float4 o;
        o.x = fmaxf((acc.x + bf2f(sv.x)) * di + bv.x, 0.f);
        o.y = fmaxf((acc.y + bf2f(sv.y)) * di + bv.y, 0.f);
        o.z = fmaxf((acc.z + bf2f(sv.z)) * di + bv.z, 0.f);
        o.w = fmaxf((acc.w + bf2f(sv.w)) * di + bv.w, 0.f);
        *(float4*)(out + (size_t)wid * HH + cidx) = o;
    }
}

// ---------------------------------------------------------------------------
// GCN2 aggregation (fp32, 16 lanes/node).
// ---------------------------------------------------------------------------
__global__ __launch_bounds__(256) void gcn2_agg(const float* __restrict__ h,
                                                const int* __restrict__ rs,
                                                const int* __restrict__ col,
                                                const float* __restrict__ dinv,
                                                const float* __restrict__ b,
                                                float* __restrict__ out) {
    int t = blockIdx.x * 256 + threadIdx.x;
    int node = t >> 4;
    int c = t & 15;
    if (node >= NN) return;
    float di = dinv[node];
    int beg = rs[node], end = rs[node + 1];
    float acc = h[(size_t)node * 16 + c];
    for (int j0 = beg; j0 < end; j0 += 16) {
        int cnt = min(16, end - j0);
        int sreg = 0;
        if (c < cnt) sreg = col[j0 + c];
        for (int e = 0; e < cnt; e++) {
            int s = __shfl(sreg, e, 16);
            acc += h[(size_t)s * 16 + c];
        }
    }
    out[(size_t)node * 32 + c] = acc * di + b[c];
}

// ---------------------------------------------------------------------------
// GAT layer 1 scores (hgat bf16)
// ---------------------------------------------------------------------------
__global__ __launch_bounds__(256) void s1_kernel(const unsigned short* __restrict__ hg,
                                                 const float* __restrict__ a_s,
                                                 const float* __restrict__ a_d,
                                                 float* __restrict__ ssrc,
                                                 float* __restrict__ sdst) {
    int wid = (blockIdx.x * 256 + threadIdx.x) >> 6;
    int lane = threadIdx.x & 63;
    if (wid >= NN) return;
    float ss[4], sd[4];
#pragma unroll
    for (int h = 0; h < 4; h++) {
        float v = bf2f(hg[(size_t)wid * 256 + h * 64 + lane]);
        float ps = v * a_s[h * 64 + lane];
        float pd = v * a_d[h * 64 + lane];
        for (int off = 32; off >= 1; off >>= 1) {
            ps += __shfl_xor(ps, off, 64);
            pd += __shfl_xor(pd, off, 64);
        }
        ss[h] = ps;
        sd[h] = pd;
    }
    if (lane == 0) {
        *(float4*)(ssrc + (size_t)wid * 4) = make_float4(ss[0], ss[1], ss[2], ss[3]);
        *(float4*)(sdst + (size_t)wid * 4) = make_float4(sd[0], sd[1], sd[2], sd[3]);
    }
}

// ---------------------------------------------------------------------------
// GAT1 aggregation: bf16 gather (512 B/row), no max-subtraction (|e|<~4).
// ---------------------------------------------------------------------------
__global__ __launch_bounds__(256) void gat1_agg(const unsigned short* __restrict__ hg,
                                                const int* __restrict__ rs,
                                                const int* __restrict__ col,
                                                const float* __restrict__ ssrc,
                                                const float* __restrict__ sdst,
                                                const float* __restrict__ b,
                                                float* __restrict__ out) {
    int wid = (blockIdx.x * 256 + threadIdx.x) >> 6;
    int lane = threadIdx.x & 63;
    if (wid >= NN) return;
    int hh = lane >> 4;
    float4 sd4 = *(const float4*)(sdst + (size_t)wid * 4);
    float sdv[4] = {sd4.x, sd4.y, sd4.z, sd4.w};

    float4 sf4 = *(const float4*)(ssrc + (size_t)wid * 4);
    float sfv[4] = {sf4.x, sf4.y, sf4.z, sf4.w};
    float psf[4];
#pragma unroll
    for (int h = 0; h < 4; h++) {
        float e = sfv[h] + sdv[h];
        e = (e >= 0.f) ? e : 0.2f * e;
        psf[h] = __expf(e);
    }
    float pse = (hh & 2) ? ((hh & 1) ? psf[3] : psf[2]) : ((hh & 1) ? psf[1] : psf[0]);
    ushort4 hvs = *(const ushort4*)(hg + (size_t)wid * 256 + lane * 4);
    float4 acc;
    acc.x = bf2f(hvs.x) * pse; acc.y = bf2f(hvs.y) * pse;
    acc.z = bf2f(hvs.z) * pse; acc.w = bf2f(hvs.w) * pse;

    float lsum[4] = {0.f, 0.f, 0.f, 0.f};
    int beg = rs[wid], end = rs[wid + 1];
    for (int j0 = beg; j0 < end; j0 += 64) {
        int cnt = min(64, end - j0);
        int sreg = 0;
        float pv[4] = {0.f, 0.f, 0.f, 0.f};
        if (lane < cnt) {
            sreg = col[j0 + lane];
            float4 sv = *(const float4*)(ssrc + (size_t)sreg * 4);
            float svv[4] = {sv.x, sv.y, sv.z, sv.w};
#pragma unroll
            for (int h = 0; h < 4; h++) {
                float e = svv[h] + sdv[h];
                e = (e >= 0.f) ? e : 0.2f * e;
                pv[h] = __expf(e);
                lsum[h] += pv[h];
            }
        }
        for (int e = 0; e < cnt; e++) {
            int s = __shfl(sreg, e, 64);
            float p0 = __shfl(pv[0], e, 64);
            float p1 = __shfl(pv[1], e, 64);
            float p2 = __shfl(pv[2], e, 64);
            float p3 = __shfl(pv[3], e, 64);
            float p = (hh & 2) ? ((hh & 1) ? p3 : p2) : ((hh & 1) ? p1 : p0);
            ushort4 hv = *(const ushort4*)(hg + (size_t)s * 256 + lane * 4);
            acc.x += bf2f(hv.x) * p; acc.y += bf2f(hv.y) * p;
            acc.z += bf2f(hv.z) * p; acc.w += bf2f(hv.w) * p;
        }
    }
#pragma unroll
    for (int h = 0; h < 4; h++) {
        float v = lsum[h];
        for (int off = 32; off >= 1; off >>= 1) v += __shfl_xor(v, off, 64);
        lsum[h] = v + psf[h];
    }
    float lt = (hh & 2) ? ((hh & 1) ? lsum[3] : lsum[2]) : ((hh & 1) ? lsum[1] : lsum[0]);
    float li = 1.0f / lt;
    float4 bv = *(const float4*)(b + lane * 4);
    float4 o;
    o.x = fmaxf(acc.x * li + bv.x, 0.f);
    o.y = fmaxf(acc.y * li + bv.y, 0.f);
    o.z = fmaxf(acc.z * li + bv.z, 0.f);
    o.w = fmaxf(acc.w * li + bv.w, 0.f);
    *(float4*)(out + (size_t)wid * 256 + lane * 4) = o;
}

// ---------------------------------------------------------------------------
// GAT layer 2 (heads=1, C=16) — fp32.
// ---------------------------------------------------------------------------
__global__ __launch_bounds__(256) void s2_kernel(const float* __restrict__ hg,
                                                 const float* __restrict__ a_s,
                                                 const float* __restrict__ a_d,
                                                 float* __restrict__ ssrc,
                                                 float* __restrict__ sdst) {
    int t = blockIdx.x * 256 + threadIdx.x;
    int node = t >> 4;
    int c = t & 15;
    if (node >= NN) return;
    float v = hg[(size_t)node * 16 + c];
    float ps = v * a_s[c];
    float pd = v * a_d[c];
    for (int off = 8; off >= 1; off >>= 1) {
        ps += __shfl_xor(ps, off, 16);
        pd += __shfl_xor(pd, off, 16);
    }
    if (c == 0) {
        ssrc[node] = ps;
        sdst[node] = pd;
    }
}

__global__ __launch_bounds__(256) void gat2_agg(const float* __restrict__ hg,
                                                const int* __restrict__ rs,
                                                const int* __restrict__ col,
                                                const float* __restrict__ ssrc,
                                                const float* __restrict__ sdst,
                                                const float* __restrict__ b,
                                                float* __restrict__ out) {
    int t = blockIdx.x * 256 + threadIdx.x;
    int node = t >> 4;
    int c = t & 15;
    if (node >= NN) return;
    float sd = sdst[node];
    float es = ssrc[node] + sd;
    es = (es >= 0.f) ? es : 0.2f * es;
    float psf = __expf(es);
    float acc = hg[(size_t)node * 16 + c] * psf;
    float lp = 0.f;
    int beg = rs[node], end = rs[node + 1];
    for (int j0 = beg; j0 < end; j0 += 16) {
        int cnt = min(16, end - j0);
        int sreg = 0;
        float pr = 0.f;
        if (c < cnt) {
            sreg = col[j0 + c];
            float e = ssrc[sreg] + sd;
            e = (e >= 0.f) ? e : 0.2f * e;
            pr = __expf(e);
            lp += pr;
        }
        for (int e = 0; e < cnt; e++) {
            int s = __shfl(sreg, e, 16);
            float p = __shfl(pr, e, 16);
            acc += hg[(size_t)s * 16 + c] * p;
        }
    }
    for (int off = 8; off >= 1; off >>= 1) lp += __shfl_xor(lp, off, 16);
    float l = lp + psf;
    out[(size_t)node * 32 + 16 + c] = acc / l + b[c];
}

// ---------------------------------------------------------------------------
// Launch
// ---------------------------------------------------------------------------
extern "C" void kernel_launch(void* const* d_in, const int* in_sizes, int n_in,
                              void* d_out, int out_size, void* d_ws, size_t ws_size,
                              hipStream_t stream) {
    const float* x      = (const float*)d_in[0];
    const int*   ei     = (const int*)d_in[1];
    const float* Wg1    = (const float*)d_in[2];
    const float* bg1    = (const float*)d_in[3];
    const float* Wg2    = (const float*)d_in[4];
    const float* bg2    = (const float*)d_in[5];
    const float* Wgat1  = (const float*)d_in[6];
    const float* a_src1 = (const float*)d_in[7];
    const float* a_dst1 = (const float*)d_in[8];
    const float* bgat1  = (const float*)d_in[9];
    const float* Wgat2  = (const float*)d_in[10];
    const float* a_src2 = (const float*)d_in[11];
    const float* a_dst2 = (const float*)d_in[12];
    const float* bgat2  = (const float*)d_in[13];
    float* out = (float*)d_out;

    const int* e_src = ei;
    const int* e_dst = ei + EE;

    char* wsb = (char*)d_ws;
    size_t o = 0;
    auto alloc = [&](size_t bytes) -> void* {
        void* p = wsb + o;
        o += (bytes + 255) & ~(size_t)255;
        return p;
    };
    float* dinv            = (float*)alloc(NN * 4);
    float* ssrc1           = (float*)alloc((size_t)NN * 16);
    float* sdst1           = (float*)alloc((size_t)NN * 16);
    unsigned short* h1b    = (unsigned short*)alloc((size_t)NN * HH * 2);
    float* xg1             = (float*)alloc((size_t)NN * HH * 4);
    float* h2              = (float*)alloc((size_t)NN * 16 * 4);
    unsigned short* hgb    = (unsigned short*)alloc((size_t)NN * 256 * 2);
    float* xgat1           = (float*)alloc((size_t)NN * 256 * 4);
    float* h2g             = (float*)alloc((size_t)NN * 16 * 4);
    float* s2src           = (float*)alloc(NN * 4);
    float* s2dst           = (float*)alloc(NN * 4);
    unsigned short* bhi1   = (unsigned short*)alloc(256 * 64 * 2);
    unsigned short* blo1   = (unsigned short*)alloc(256 * 64 * 2);
    unsigned short* bhi2   = (unsigned short*)alloc(256 * 256 * 2);
    unsigned short* blo2   = (unsigned short*)alloc(256 * 256 * 2);
    int* cnt               = (int*)alloc(NN * 4);
    int* rowstart          = (int*)alloc((NN + 1) * 4);
    int* cursor            = (int*)alloc(NN * 4);
    int* colarr            = (int*)alloc((size_t)EE * 4);
    int* partial           = (int*)alloc(256 * 4);
    int* blockoff          = (int*)alloc(256 * 4);

    const int TB = 256;
    const int NB = (NN + 255) / 256;  // 196 scan blocks
    // CSR build + weight packing
    k_zero_int<<<(NN + TB - 1) / TB, TB, 0, stream>>>(cnt, NN);
    k_count<<<(EE + TB - 1) / TB, TB, 0, stream>>>(e_dst, cnt, EE);
    k_scan_a<<<NB, TB, 0, stream>>>(cnt, partial, NN);
    k_scan_b<<<1, TB, 0, stream>>>(partial, blockoff, rowstart + NN, NB);
    k_scan_c<<<NB, TB, 0, stream>>>(cnt, blockoff, rowstart, cursor, dinv, NN);
    k_fill<<<(EE + TB - 1) / TB, TB, 0, stream>>>(e_src, e_dst, cursor, colarr, EE);
    k_pack_w<4><<<(8 * 4 * 64 + TB - 1) / TB, TB, 0, stream>>>(Wg1, bhi1, blo1);
    k_pack_w<16><<<(8 * 16 * 64 + TB - 1) / TB, TB, 0, stream>>>(Wgat1, bhi2, blo2);

    const int GB = (NN + 63) / 64;
    // GCN path (h1 bf16, pre-scaled by dinv)
    mfma_gemm<4, true><<<GB, TB, 0, stream>>>(x, bhi1, blo1, h1b, dinv, NN);
    gcn1_agg<<<(NN * 64 + TB - 1) / TB, TB, 0, stream>>>(h1b, rowstart, colarr, dinv, bg1, xg1);
    gemm_n16<HH><<<(NN * 16 + TB - 1) / TB, TB, 0, stream>>>(xg1, Wg2, h2, NN, dinv);
    gcn2_agg<<<(NN * 16 + TB - 1) / TB, TB, 0, stream>>>(h2, rowstart, colarr, dinv, bg2, out);

    // GAT path (hgat bf16)
    mfma_gemm<16, false><<<GB, TB, 0, stream>>>(x, bhi2, blo2, hgb, nullptr, NN);
    s1_kernel<<<(NN * 64 + TB - 1) / TB, TB, 0, stream>>>(hgb, a_src1, a_dst1, ssrc1, sdst1);
    gat1_agg<<<(NN * 64 + TB - 1) / TB, TB, 0, stream>>>(hgb, rowstart, colarr, ssrc1, sdst1, bgat1, xgat1);
    gemm_n16<NHEADS * HH><<<(NN * 16 + TB - 1) / TB, TB, 0, stream>>>(xgat1, Wgat2, h2g, NN, nullptr);
    s2_kernel<<<(NN * 16 + TB - 1) / TB, TB, 0, stream>>>(h2g, a_src2, a_dst2, s2src, s2dst);
    gat2_agg<<<(NN * 16 + TB - 1) / TB, TB, 0, stream>>>(h2g, rowstart, colarr, s2src, s2dst, bgat2, out);
}

// Round 6
// 432.813 us; speedup vs baseline: 1.8862x; 1.1445x over previous
//
#include <hip/hip_runtime.h>
#include <math.h>

#define NN     50000
#define FF     256
#define HH     64
#define NHEADS 4
#define EE     800000
#define OUTD   16

typedef __attribute__((ext_vector_type(8))) short short8;
typedef __attribute__((ext_vector_type(4))) float f32x4;

__device__ inline unsigned short f2bf(float f) {
    unsigned u = __builtin_bit_cast(unsigned, f);
    unsigned r = (u + 0x7fff + ((u >> 16) & 1)) >> 16;
    return (unsigned short)r;
}
__device__ inline float bf2f(unsigned short s) {
    unsigned u = ((unsigned)s) << 16;
    return __builtin_bit_cast(float, u);
}

// ---------------------------------------------------------------------------
// CSR build (3-phase hierarchical scan — round-4 lesson).
// ---------------------------------------------------------------------------
__global__ void k_zero_int(int* __restrict__ p, int n) {
    int i = blockIdx.x * blockDim.x + threadIdx.x;
    if (i < n) p[i] = 0;
}

__global__ void k_count(const int* __restrict__ dst, int* __restrict__ cnt, int e) {
    int i = blockIdx.x * blockDim.x + threadIdx.x;
    if (i < e) atomicAdd(&cnt[dst[i]], 1);
}

__global__ __launch_bounds__(256) void k_scan_a(const int* __restrict__ cnt,
                                                int* __restrict__ partial, int n) {
    int i = blockIdx.x * 256 + threadIdx.x;
    int v = (i < n) ? cnt[i] : 0;
#pragma unroll
    for (int off = 32; off >= 1; off >>= 1) v += __shfl_xor(v, off, 64);
    __shared__ int ws[4];
    int wave = threadIdx.x >> 6;
    if ((threadIdx.x & 63) == 0) ws[wave] = v;
    __syncthreads();
    if (threadIdx.x == 0) partial[blockIdx.x] = ws[0] + ws[1] + ws[2] + ws[3];
}

__global__ __launch_bounds__(256) void k_scan_b(const int* __restrict__ partial,
                                                int* __restrict__ blockoff,
                                                int* __restrict__ total_out, int nb) {
    __shared__ int arr[256];
    int tid = threadIdx.x;
    arr[tid] = (tid < nb) ? partial[tid] : 0;
    __syncthreads();
#pragma unroll
    for (int off = 1; off < 256; off <<= 1) {
        int v = arr[tid];
        int add = (tid >= off) ? arr[tid - off] : 0;
        __syncthreads();
        arr[tid] = v + add;
        __syncthreads();
    }
    if (tid < nb) blockoff[tid] = arr[tid] - partial[tid];
    if (tid == 0) *total_out = arr[255];
}

__global__ __launch_bounds__(256) void k_scan_c(const int* __restrict__ cnt,
                                                const int* __restrict__ blockoff,
                                                int* __restrict__ row_start,
                                                int* __restrict__ cursor,
                                                float* __restrict__ dinv, int n) {
    __shared__ int arr[256];
    int tid = threadIdx.x;
    int i = blockIdx.x * 256 + tid;
    int c = (i < n) ? cnt[i] : 0;
    arr[tid] = c;
    __syncthreads();
#pragma unroll
    for (int off = 1; off < 256; off <<= 1) {
        int v = arr[tid];
        int add = (tid >= off) ? arr[tid - off] : 0;
        __syncthreads();
        arr[tid] = v + add;
        __syncthreads();
    }
    if (i < n) {
        int excl = arr[tid] - c + blockoff[blockIdx.x];
        row_start[i] = excl;
        cursor[i] = excl;
        dinv[i] = rsqrtf((float)(c + 1));
    }
}

__global__ void k_fill(const int* __restrict__ src, const int* __restrict__ dst,
                       int* __restrict__ cursor, int* __restrict__ col, int e) {
    int i = blockIdx.x * blockDim.x + threadIdx.x;
    if (i < e) {
        int d = dst[i];
        int pos = atomicAdd(&cursor[d], 1);
        col[pos] = src[i];
    }
}

// ---------------------------------------------------------------------------
// Pack W into MFMA B-fragment layout, split hi/lo bf16.
// ---------------------------------------------------------------------------
template <int NT>
__global__ void k_pack_w(const float* __restrict__ W,
                         unsigned short* __restrict__ bhi,
                         unsigned short* __restrict__ blo) {
    int t_ = blockIdx.x * blockDim.x + threadIdx.x;
    const int total = 8 * NT * 64;
    if (t_ >= total) return;
    int lane = t_ & 63;
    int tile = (t_ >> 6) % NT;
    int kb = (t_ >> 6) / NT;
    int q = lane >> 4, c = lane & 15;
    const int NC = NT * 16;
    size_t off = ((size_t)(kb * NT + tile) * 64 + lane) * 8;
#pragma unroll
    for (int j = 0; j < 8; j++) {
        float w = W[(size_t)(kb * 32 + q * 8 + j) * NC + tile * 16 + c];
        unsigned short h = f2bf(w);
        bhi[off + j] = h;
        blo[off + j] = f2bf(w - bf2f(h));
    }
}

// ---------------------------------------------------------------------------
// MFMA GEMM (bf16x2 compensation). If SCORES: fused s1 — per-row per-head
// dots with a_s/a_d (head = tile>>2 since col n = t*16+c, head = n>>6).
// ---------------------------------------------------------------------------
template <int NT, bool SCALE, bool SCORES>
__global__ __launch_bounds__(256) void mfma_gemm(const float* __restrict__ A,
                                                 const unsigned short* __restrict__ Bhi,
                                                 const unsigned short* __restrict__ Blo,
                                                 unsigned short* __restrict__ Cbf,
                                                 const float* __restrict__ rowscale,
                                                 const float* __restrict__ a_s,
                                                 const float* __restrict__ a_d,
                                                 float* __restrict__ ssrc,
                                                 float* __restrict__ sdst,
                                                 int M) {
    const int K = 256, NC = NT * 16;
    int tid = threadIdx.x;
    int w = tid >> 6, lane = tid & 63, q = lane >> 4, c = lane & 15;
    int row_base = blockIdx.x * 64 + w * 16;
    int ar = min(row_base + c, M - 1);
    const float* ap = A + (size_t)ar * K + q * 8;

    f32x4 acc[NT];
#pragma unroll
    for (int t = 0; t < NT; t++) acc[t] = (f32x4){0.f, 0.f, 0.f, 0.f};

    for (int kb = 0; kb < 8; kb++) {
        float av[8];
        *(float4*)(av)     = *(const float4*)(ap + kb * 32);
        *(float4*)(av + 4) = *(const float4*)(ap + kb * 32 + 4);
        short8 ahi, alo;
#pragma unroll
        for (int j = 0; j < 8; j++) {
            unsigned short h = f2bf(av[j]);
            ahi[j] = (short)h;
            alo[j] = (short)f2bf(av[j] - bf2f(h));
        }
#pragma unroll
        for (int t = 0; t < NT; t++) {
            size_t bo = ((size_t)(kb * NT + t) * 64 + lane) * 8;
            short8 bhi = *(const short8*)(Bhi + bo);
            short8 blo = *(const short8*)(Blo + bo);
            acc[t] = __builtin_amdgcn_mfma_f32_16x16x32_bf16(ahi, bhi, acc[t], 0, 0, 0);
            acc[t] = __builtin_amdgcn_mfma_f32_16x16x32_bf16(alo, bhi, acc[t], 0, 0, 0);
            acc[t] = __builtin_amdgcn_mfma_f32_16x16x32_bf16(ahi, blo, acc[t], 0, 0, 0);
        }
    }

    if (SCORES) {
        // uniform flow: shfls safe (no early returns in this kernel)
#pragma unroll
        for (int i = 0; i < 4; i++) {
            int r = row_base + q * 4 + i;
            float ss[4] = {0.f, 0.f, 0.f, 0.f};
            float sd[4] = {0.f, 0.f, 0.f, 0.f};
#pragma unroll
            for (int t = 0; t < NT; t++) {
                float v = acc[t][i];
                ss[t >> 2] += v * a_s[t * 16 + c];
                sd[t >> 2] += v * a_d[t * 16 + c];
            }
#pragma unroll
            for (int h = 0; h < 4; h++) {
#pragma unroll
                for (int off = 1; off <= 8; off <<= 1) {
                    ss[h] += __shfl_xor(ss[h], off, 16);
                    sd[h] += __shfl_xor(sd[h], off, 16);
                }
            }
            if (c == i && r < M) {
                *(float4*)(ssrc + (size_t)r * 4) = make_float4(ss[0], ss[1], ss[2], ss[3]);
                *(float4*)(sdst + (size_t)r * 4) = make_float4(sd[0], sd[1], sd[2], sd[3]);
            }
        }
    }

#pragma unroll
    for (int i = 0; i < 4; i++) {
        int r = row_base + q * 4 + i;
        if (r < M) {
            float sc = SCALE ? rowscale[r] : 1.0f;
#pragma unroll
            for (int t = 0; t < NT; t++)
                Cbf[(size_t)r * NC + t * 16 + c] = f2bf(acc[t][i] * sc);
        }
    }
}

// ---------------------------------------------------------------------------
// GEMM KOUT=16, bf16 input. If SC2: fused s2 (16-lane row dot + reduce).
// Grid is exact (NN*16 % 256 == 0) -> no early return, shfls full-exec.
// ---------------------------------------------------------------------------
template <int KIN, bool SCALE, bool SC2>
__global__ __launch_bounds__(256) void gemm_n16(const unsigned short* __restrict__ A,
                                                const float* __restrict__ W,
                                                float* __restrict__ C, int M,
                                                const float* __restrict__ rowscale,
                                                const float* __restrict__ a_s2,
                                                const float* __restrict__ a_d2,
                                                float* __restrict__ s2s,
                                                float* __restrict__ s2d) {
    __shared__ float Ws[KIN * 16];
    for (int i = threadIdx.x; i < KIN * 16; i += 256) Ws[i] = W[i];
    __syncthreads();
    int t = blockIdx.x * 256 + threadIdx.x;
    int row = t >> 4;
    int c = t & 15;
    const unsigned short* a = A + (size_t)row * KIN;
    float acc = 0.f;
#pragma unroll 8
    for (int k = 0; k < KIN; k += 4) {
        ushort4 av = *(const ushort4*)(a + k);
        acc += bf2f(av.x) * Ws[(k + 0) * 16 + c];
        acc += bf2f(av.y) * Ws[(k + 1) * 16 + c];
        acc += bf2f(av.z) * Ws[(k + 2) * 16 + c];
        acc += bf2f(av.w) * Ws[(k + 3) * 16 + c];
    }
    if (SC2) {
        float ps = acc * a_s2[c];
        float pd = acc * a_d2[c];
#pragma unroll
        for (int off = 1; off <= 8; off <<= 1) {
            ps += __shfl_xor(ps, off, 16);
            pd += __shfl_xor(pd, off, 16);
        }
        if (c == 0) {
            s2s[row] = ps;
            s2d[row] = pd;
        }
    }
    float sc = SCALE ? rowscale[row] : 1.0f;
    C[(size_t)row * 16 + c] = acc * sc;
}

// ---------------------------------------------------------------------------
// GCN1 aggregation, h1 bf16 (128 B/row), pre-scaled by dinv; out bf16.
// ---------------------------------------------------------------------------
__global__ __launch_bounds__(256) void gcn1_agg(const unsigned short* __restrict__ h,
                                                const int* __restrict__ rs,
                                                const int* __restrict__ col,
                                                const float* __restrict__ dinv,
                                                const float* __restrict__ b,
                                                unsigned short* __restrict__ out) {
    int wid = (blockIdx.x * 256 + threadIdx.x) >> 6;
    int lane = threadIdx.x & 63;
    if (wid >= NN) return;
    int g = lane >> 4;
    int cidx = (lane & 15) * 4;
    float di = dinv[wid];
    int beg = rs[wid], end = rs[wid + 1];
    float4 acc = make_float4(0.f, 0.f, 0.f, 0.f);

    for (int j0 = beg; j0 < end; j0 += 64) {
        int cnt = min(64, end - j0);
        int sreg = 0;
        if (lane < cnt) sreg = col[j0 + lane];
        for (int e = 0; e < cnt; e += 4) {
            int myE = e + g;
            int s = __shfl(sreg, myE, 64);   // unconditional (round-2 lesson)
            if (myE < cnt) {
                ushort4 v = *(const ushort4*)(h + (size_t)s * HH + cidx);
                acc.x += bf2f(v.x); acc.y += bf2f(v.y);
                acc.z += bf2f(v.z); acc.w += bf2f(v.w);
            }
        }
    }
#pragma unroll
    for (int off = 16; off <= 32; off <<= 1) {
        acc.x += __shfl_xor(acc.x, off, 64);
        acc.y += __shfl_xor(acc.y, off, 64);
        acc.z += __shfl_xor(acc.z, off, 64);
        acc.w += __shfl_xor(acc.w, off, 64);
    }
    if (g == 0) {
        ushort4 sv = *(const ushort4*)(h + (size_t)wid * HH + cidx);
        float4 bv = *(const float4*)(b + cidx);
        ushort4 o;
        o.x = f2bf(fmaxf((acc.x + bf2f(sv.x)) * di + bv.x, 0.f));
        o.y = f2bf(fmaxf((acc.y + bf2f(sv.y)) * di + bv.y, 0.f));
        o.z = f2bf(fmaxf((acc.z + bf2f(sv.z)) * di + bv.z, 0.f));
        o.w = f2bf(fmaxf((acc.w + bf2f(sv.w)) * di + bv.w, 0.f));
        *(ushort4*)(out + (size_t)wid * HH + cidx) = o;
    }
}

// ---------------------------------------------------------------------------
// GAT1 aggregation: LDS-staged p/src (2 broadcast ds_reads per edge instead
// of 5 bpermutes — round-5 DS-pipe analysis). bf16 gather, out bf16.
// ---------------------------------------------------------------------------
__global__ __launch_bounds__(256) void gat1_agg(const unsigned short* __restrict__ hg,
                                                const int* __restrict__ rs,
                                                const int* __restrict__ col,
                                                const float* __restrict__ ssrc,
                                                const float* __restrict__ sdst,
                                                const float* __restrict__ b,
                                                unsigned short* __restrict__ out) {
    __shared__ int s_lds[4][64];
    __shared__ float p_lds[4][64 * 4];
    int tid = threadIdx.x;
    int w = tid >> 6, lane = tid & 63;
    int wid = blockIdx.x * 4 + w;       // grid exact: 12500*4 = NN
    int hh = lane >> 4;
    int* sl = s_lds[w];
    float* pl = p_lds[w];

    float4 sd4 = *(const float4*)(sdst + (size_t)wid * 4);
    float sdv[4] = {sd4.x, sd4.y, sd4.z, sd4.w};
    float4 sf4 = *(const float4*)(ssrc + (size_t)wid * 4);
    float sfv[4] = {sf4.x, sf4.y, sf4.z, sf4.w};
    float psf[4];
#pragma unroll
    for (int h = 0; h < 4; h++) {
        float e = sfv[h] + sdv[h];
        e = (e >= 0.f) ? e : 0.2f * e;
        psf[h] = __expf(e);
    }
    float pse = (hh & 2) ? ((hh & 1) ? psf[3] : psf[2]) : ((hh & 1) ? psf[1] : psf[0]);
    ushort4 hvs = *(const ushort4*)(hg + (size_t)wid * 256 + lane * 4);
    float4 acc;
    acc.x = bf2f(hvs.x) * pse; acc.y = bf2f(hvs.y) * pse;
    acc.z = bf2f(hvs.z) * pse; acc.w = bf2f(hvs.w) * pse;

    float lsum[4] = {0.f, 0.f, 0.f, 0.f};
    int beg = rs[wid], end = rs[wid + 1];
    for (int j0 = beg; j0 < end; j0 += 64) {
        int cnt = min(64, end - j0);
        if (lane < cnt) {
            int sreg = col[j0 + lane];
            float4 sv = *(const float4*)(ssrc + (size_t)sreg * 4);
            float svv[4] = {sv.x, sv.y, sv.z, sv.w};
            float pv[4];
#pragma unroll
            for (int h = 0; h < 4; h++) {
                float e = svv[h] + sdv[h];
                e = (e >= 0.f) ? e : 0.2f * e;
                pv[h] = __expf(e);
                lsum[h] += pv[h];
            }
            sl[lane] = sreg;
            *(float4*)&pl[lane * 4] = make_float4(pv[0], pv[1], pv[2], pv[3]);
        }
        // same-wave LDS write->read: DS pipe is in-order per wave, no barrier
        for (int e = 0; e < cnt; e++) {
            int s = sl[e];                 // broadcast read
            float p = pl[e * 4 + hh];      // broadcast within 16-lane group
            ushort4 hv = *(const ushort4*)(hg + (size_t)s * 256 + lane * 4);
            acc.x += bf2f(hv.x) * p; acc.y += bf2f(hv.y) * p;
            acc.z += bf2f(hv.z) * p; acc.w += bf2f(hv.w) * p;
        }
    }
#pragma unroll
    for (int h = 0; h < 4; h++) {
        float v = lsum[h];
        for (int off = 32; off >= 1; off >>= 1) v += __shfl_xor(v, off, 64);
        lsum[h] = v + psf[h];
    }
    float lt = (hh & 2) ? ((hh & 1) ? lsum[3] : lsum[2]) : ((hh & 1) ? lsum[1] : lsum[0]);
    float li = 1.0f / lt;
    float4 bv = *(const float4*)(b + lane * 4);
    ushort4 o;
    o.x = f2bf(fmaxf(acc.x * li + bv.x, 0.f));
    o.y = f2bf(fmaxf(acc.y * li + bv.y, 0.f));
    o.z = f2bf(fmaxf(acc.z * li + bv.z, 0.f));
    o.w = f2bf(fmaxf(acc.w * li + bv.w, 0.f));
    *(ushort4*)(out + (size_t)wid * 256 + lane * 4) = o;
}

// ---------------------------------------------------------------------------
// Final aggregation: fused GCN2 + GAT2 (shared CSR walk), writes both output
// halves. 16 lanes per node. Grid exact (NN*16 % 256 == 0).
// ---------------------------------------------------------------------------
__global__ __launch_bounds__(256) void final_agg(const float* __restrict__ h2,
                                                 const float* __restrict__ h2g,
                                                 const int* __restrict__ rs,
                                                 const int* __restrict__ col,
                                                 const float* __restrict__ dinv,
                                                 const float* __restrict__ s2s,
                                                 const float* __restrict__ s2d,
                                                 const float* __restrict__ bg2,
                                                 const float* __restrict__ bga2,
                                                 float* __restrict__ out) {
    int t = blockIdx.x * 256 + threadIdx.x;
    int node = t >> 4;
    int c = t & 15;
    float di = dinv[node];
    float sd = s2d[node];
    float es = s2s[node] + sd;
    es = (es >= 0.f) ? es : 0.2f * es;
    float psf = __expf(es);
    float accg = h2[(size_t)node * 16 + c];          // self (pre-scaled by dinv)
    float acca = h2g[(size_t)node * 16 + c] * psf;   // self
    float lp = 0.f;
    int beg = rs[node], end = rs[node + 1];
    for (int j0 = beg; j0 < end; j0 += 16) {
        int cnt = min(16, end - j0);
        int sreg = 0;
        float pr = 0.f;
        if (c < cnt) {
            sreg = col[j0 + c];
            float e = s2s[sreg] + sd;
            e = (e >= 0.f) ? e : 0.2f * e;
            pr = __expf(e);
            lp += pr;
        }
        for (int e = 0; e < cnt; e++) {
            int s = __shfl(sreg, e, 16);
            float p = __shfl(pr, e, 16);
            accg += h2[(size_t)s * 16 + c];
            acca += h2g[(size_t)s * 16 + c] * p;
        }
    }
    for (int off = 8; off >= 1; off >>= 1) lp += __shfl_xor(lp, off, 16);
    float l = lp + psf;
    out[(size_t)node * 32 + c] = accg * di + bg2[c];
    out[(size_t)node * 32 + 16 + c] = acca / l + bga2[c];
}

// ---------------------------------------------------------------------------
// Launch
// ---------------------------------------------------------------------------
extern "C" void kernel_launch(void* const* d_in, const int* in_sizes, int n_in,
                              void* d_out, int out_size, void* d_ws, size_t ws_size,
                              hipStream_t stream) {
    const float* x      = (const float*)d_in[0];
    const int*   ei     = (const int*)d_in[1];
    const float* Wg1    = (const float*)d_in[2];
    const float* bg1    = (const float*)d_in[3];
    const float* Wg2    = (const float*)d_in[4];
    const float* bg2    = (const float*)d_in[5];
    const float* Wgat1  = (const float*)d_in[6];
    const float* a_src1 = (const float*)d_in[7];
    const float* a_dst1 = (const float*)d_in[8];
    const float* bgat1  = (const float*)d_in[9];
    const float* Wgat2  = (const float*)d_in[10];
    const float* a_src2 = (const float*)d_in[11];
    const float* a_dst2 = (const float*)d_in[12];
    const float* bgat2  = (const float*)d_in[13];
    float* out = (float*)d_out;

    const int* e_src = ei;
    const int* e_dst = ei + EE;

    char* wsb = (char*)d_ws;
    size_t o = 0;
    auto alloc = [&](size_t bytes) -> void* {
        void* p = wsb + o;
        o += (bytes + 255) & ~(size_t)255;
        return p;
    };
    float* dinv            = (float*)alloc(NN * 4);
    float* ssrc1           = (float*)alloc((size_t)NN * 16);
    float* sdst1           = (float*)alloc((size_t)NN * 16);
    unsigned short* h1b    = (unsigned short*)alloc((size_t)NN * HH * 2);
    unsigned short* xg1    = (unsigned short*)alloc((size_t)NN * HH * 2);
    float* h2              = (float*)alloc((size_t)NN * 16 * 4);
    unsigned short* hgb    = (unsigned short*)alloc((size_t)NN * 256 * 2);
    unsigned short* xgat1  = (unsigned short*)alloc((size_t)NN * 256 * 2);
    float* h2g             = (float*)alloc((size_t)NN * 16 * 4);
    float* s2src           = (float*)alloc(NN * 4);
    float* s2dst           = (float*)alloc(NN * 4);
    unsigned short* bhi1   = (unsigned short*)alloc(256 * 64 * 2);
    unsigned short* blo1   = (unsigned short*)alloc(256 * 64 * 2);
    unsigned short* bhi2   = (unsigned short*)alloc(256 * 256 * 2);
    unsigned short* blo2   = (unsigned short*)alloc(256 * 256 * 2);
    int* cnt               = (int*)alloc(NN * 4);
    int* rowstart          = (int*)alloc((NN + 1) * 4);
    int* cursor            = (int*)alloc(NN * 4);
    int* colarr            = (int*)alloc((size_t)EE * 4);
    int* partial           = (int*)alloc(256 * 4);
    int* blockoff          = (int*)alloc(256 * 4);

    const int TB = 256;
    const int NB = (NN + 255) / 256;
    // CSR build + weight packing
    k_zero_int<<<(NN + TB - 1) / TB, TB, 0, stream>>>(cnt, NN);
    k_count<<<(EE + TB - 1) / TB, TB, 0, stream>>>(e_dst, cnt, EE);
    k_scan_a<<<NB, TB, 0, stream>>>(cnt, partial, NN);
    k_scan_b<<<1, TB, 0, stream>>>(partial, blockoff, rowstart + NN, NB);
    k_scan_c<<<NB, TB, 0, stream>>>(cnt, blockoff, rowstart, cursor, dinv, NN);
    k_fill<<<(EE + TB - 1) / TB, TB, 0, stream>>>(e_src, e_dst, cursor, colarr, EE);
    k_pack_w<4><<<(8 * 4 * 64 + TB - 1) / TB, TB, 0, stream>>>(Wg1, bhi1, blo1);
    k_pack_w<16><<<(8 * 16 * 64 + TB - 1) / TB, TB, 0, stream>>>(Wgat1, bhi2, blo2);

    const int GB = (NN + 63) / 64;
    const int G16 = (NN * 16) / 256;  // exact: 3125

    // GCN path (h1 bf16 pre-scaled by dinv; xg1 bf16; h2 fp32 pre-scaled)
    mfma_gemm<4, true, false><<<GB, TB, 0, stream>>>(x, bhi1, blo1, h1b, dinv,
                                                     nullptr, nullptr, nullptr, nullptr, NN);
    gcn1_agg<<<(NN * 64) / TB, TB, 0, stream>>>(h1b, rowstart, colarr, dinv, bg1, xg1);
    gemm_n16<HH, true, false><<<G16, TB, 0, stream>>>(xg1, Wg2, h2, NN, dinv,
                                                      nullptr, nullptr, nullptr, nullptr);

    // GAT path (hgat bf16 + fused s1; xgat1 bf16; h2g fp32 + fused s2)
    mfma_gemm<16, false, true><<<GB, TB, 0, stream>>>(x, bhi2, blo2, hgb, nullptr,
                                                      a_src1, a_dst1, ssrc1, sdst1, NN);
    gat1_agg<<<NN / 4, TB, 0, stream>>>(hgb, rowstart, colarr, ssrc1, sdst1, bgat1, xgat1);
    gemm_n16<NHEADS * HH, false, true><<<G16, TB, 0, stream>>>(xgat1, Wgat2, h2g, NN, nullptr,
                                                               a_src2, a_dst2, s2src, s2dst);

    // Fused GCN2+GAT2 aggregation -> d_out
    final_agg<<<G16, TB, 0, stream>>>(h2, h2g, rowstart, colarr, dinv,
                                      s2src, s2dst, bg2, bgat2, out);
}

// Round 8
// 376.664 us; speedup vs baseline: 2.1673x; 1.1491x over previous
//
#include <hip/hip_runtime.h>
#include <math.h>

#define NN     50000
#define FF     256
#define HH     64
#define NHEADS 4
#define EE     800000
#define OUTD   16

typedef __attribute__((ext_vector_type(8))) short short8;
typedef __attribute__((ext_vector_type(4))) float f32x4;

__device__ inline unsigned short f2bf(float f) {
    unsigned u = __builtin_bit_cast(unsigned, f);
    unsigned r = (u + 0x7fff + ((u >> 16) & 1)) >> 16;
    return (unsigned short)r;
}
__device__ inline float bf2f(unsigned short s) {
    unsigned u = ((unsigned)s) << 16;
    return __builtin_bit_cast(float, u);
}

// ---------------------------------------------------------------------------
// CSR build (3-phase hierarchical scan — round-4 lesson).
// ---------------------------------------------------------------------------
__global__ void k_zero_int(int* __restrict__ p, int n) {
    int i = blockIdx.x * blockDim.x + threadIdx.x;
    if (i < n) p[i] = 0;
}

__global__ void k_count(const int* __restrict__ dst, int* __restrict__ cnt, int e) {
    int i = blockIdx.x * blockDim.x + threadIdx.x;
    if (i < e) atomicAdd(&cnt[dst[i]], 1);
}

__global__ __launch_bounds__(256) void k_scan_a(const int* __restrict__ cnt,
                                                int* __restrict__ partial, int n) {
    int i = blockIdx.x * 256 + threadIdx.x;
    int v = (i < n) ? cnt[i] : 0;
#pragma unroll
    for (int off = 32; off >= 1; off >>= 1) v += __shfl_xor(v, off, 64);
    __shared__ int ws[4];
    int wave = threadIdx.x >> 6;
    if ((threadIdx.x & 63) == 0) ws[wave] = v;
    __syncthreads();
    if (threadIdx.x == 0) partial[blockIdx.x] = ws[0] + ws[1] + ws[2] + ws[3];
}

__global__ __launch_bounds__(256) void k_scan_b(const int* __restrict__ partial,
                                                int* __restrict__ blockoff,
                                                int* __restrict__ total_out, int nb) {
    __shared__ int arr[256];
    int tid = threadIdx.x;
    arr[tid] = (tid < nb) ? partial[tid] : 0;
    __syncthreads();
#pragma unroll
    for (int off = 1; off < 256; off <<= 1) {
        int v = arr[tid];
        int add = (tid >= off) ? arr[tid - off] : 0;
        __syncthreads();
        arr[tid] = v + add;
        __syncthreads();
    }
    if (tid < nb) blockoff[tid] = arr[tid] - partial[tid];
    if (tid == 0) *total_out = arr[255];
}

__global__ __launch_bounds__(256) void k_scan_c(const int* __restrict__ cnt,
                                                const int* __restrict__ blockoff,
                                                int* __restrict__ row_start,
                                                int* __restrict__ cursor,
                                                float* __restrict__ dinv, int n) {
    __shared__ int arr[256];
    int tid = threadIdx.x;
    int i = blockIdx.x * 256 + tid;
    int c = (i < n) ? cnt[i] : 0;
    arr[tid] = c;
    __syncthreads();
#pragma unroll
    for (int off = 1; off < 256; off <<= 1) {
        int v = arr[tid];
        int add = (tid >= off) ? arr[tid - off] : 0;
        __syncthreads();
        arr[tid] = v + add;
        __syncthreads();
    }
    if (i < n) {
        int excl = arr[tid] - c + blockoff[blockIdx.x];
        row_start[i] = excl;
        cursor[i] = excl;
        dinv[i] = rsqrtf((float)(c + 1));
    }
}

__global__ void k_fill(const int* __restrict__ src, const int* __restrict__ dst,
                       int* __restrict__ cursor, int* __restrict__ col, int e) {
    int i = blockIdx.x * blockDim.x + threadIdx.x;
    if (i < e) {
        int d = dst[i];
        int pos = atomicAdd(&cursor[d], 1);
        col[pos] = src[i];
    }
}

// ---------------------------------------------------------------------------
// Pack W (K=KB*32 x NC=NT*16, row-major fp32) into MFMA B-fragment layout,
// split hi/lo bf16.
// ---------------------------------------------------------------------------
template <int KB, int NT>
__global__ void k_pack_w(const float* __restrict__ W,
                         unsigned short* __restrict__ bhi,
                         unsigned short* __restrict__ blo) {
    int t_ = blockIdx.x * blockDim.x + threadIdx.x;
    const int total = KB * NT * 64;
    if (t_ >= total) return;
    int lane = t_ & 63;
    int tile = (t_ >> 6) % NT;
    int kb = (t_ >> 6) / NT;
    int q = lane >> 4, c = lane & 15;
    const int NC = NT * 16;
    size_t off = ((size_t)(kb * NT + tile) * 64 + lane) * 8;
#pragma unroll
    for (int j = 0; j < 8; j++) {
        float w = W[(size_t)(kb * 32 + q * 8 + j) * NC + tile * 16 + c];
        unsigned short h = f2bf(w);
        bhi[off + j] = h;
        blo[off + j] = f2bf(w - bf2f(h));
    }
}

// ---------------------------------------------------------------------------
// MFMA GEMM (bf16x2). Bhi/Blo for the current kb staged in LDS (32 KB for
// NT=16) once per block instead of per wave — round-6 analysis: 800 MB of
// redundant L2 B-fragment traffic, /4 with staging. Fused s1 if SCORES.
// ---------------------------------------------------------------------------
template <int NT, bool SCALE, bool SCORES>
__global__ __launch_bounds__(256) void mfma_gemm(const float* __restrict__ A,
                                                 const unsigned short* __restrict__ Bhi,
                                                 const unsigned short* __restrict__ Blo,
                                                 unsigned short* __restrict__ Cbf,
                                                 const float* __restrict__ rowscale,
                                                 const float* __restrict__ a_s,
                                                 const float* __restrict__ a_d,
                                                 float* __restrict__ ssrc,
                                                 float* __restrict__ sdst,
                                                 int M) {
    const int K = 256, NC = NT * 16;
    __shared__ short8 bsh[NT * 64];
    __shared__ short8 bsl[NT * 64];
    int tid = threadIdx.x;
    int w = tid >> 6, lane = tid & 63, q = lane >> 4, c = lane & 15;
    int row_base = blockIdx.x * 64 + w * 16;
    int ar = min(row_base + c, M - 1);
    const float* ap = A + (size_t)ar * K + q * 8;

    f32x4 acc[NT];
#pragma unroll
    for (int t = 0; t < NT; t++) acc[t] = (f32x4){0.f, 0.f, 0.f, 0.f};

    for (int kb = 0; kb < 8; kb++) {
        float av[8];
        *(float4*)(av)     = *(const float4*)(ap + kb * 32);
        *(float4*)(av + 4) = *(const float4*)(ap + kb * 32 + 4);
        short8 ahi, alo;
#pragma unroll
        for (int j = 0; j < 8; j++) {
            unsigned short h = f2bf(av[j]);
            ahi[j] = (short)h;
            alo[j] = (short)f2bf(av[j] - bf2f(h));
        }
        // stage this kb's B fragments (contiguous 16 KB each) into LDS
        const short8* gh = (const short8*)(Bhi + (size_t)kb * NT * 512);
        const short8* gl = (const short8*)(Blo + (size_t)kb * NT * 512);
        __syncthreads();  // readers of previous kb done
        for (int i = tid; i < NT * 64; i += 256) {
            bsh[i] = gh[i];
            bsl[i] = gl[i];
        }
        __syncthreads();
#pragma unroll
        for (int t = 0; t < NT; t++) {
            short8 bhi = bsh[t * 64 + lane];
            short8 blo = bsl[t * 64 + lane];
            acc[t] = __builtin_amdgcn_mfma_f32_16x16x32_bf16(ahi, bhi, acc[t], 0, 0, 0);
            acc[t] = __builtin_amdgcn_mfma_f32_16x16x32_bf16(alo, bhi, acc[t], 0, 0, 0);
            acc[t] = __builtin_amdgcn_mfma_f32_16x16x32_bf16(ahi, blo, acc[t], 0, 0, 0);
        }
    }

    if (SCORES) {
#pragma unroll
        for (int i = 0; i < 4; i++) {
            int r = row_base + q * 4 + i;
            float ss[4] = {0.f, 0.f, 0.f, 0.f};
            float sd[4] = {0.f, 0.f, 0.f, 0.f};
#pragma unroll
            for (int t = 0; t < NT; t++) {
                float v = acc[t][i];
                ss[t >> 2] += v * a_s[t * 16 + c];
                sd[t >> 2] += v * a_d[t * 16 + c];
            }
#pragma unroll
            for (int h = 0; h < 4; h++) {
#pragma unroll
                for (int off = 1; off <= 8; off <<= 1) {
                    ss[h] += __shfl_xor(ss[h], off, 16);
                    sd[h] += __shfl_xor(sd[h], off, 16);
                }
            }
            if (c == i && r < M) {
                *(float4*)(ssrc + (size_t)r * 4) = make_float4(ss[0], ss[1], ss[2], ss[3]);
                *(float4*)(sdst + (size_t)r * 4) = make_float4(sd[0], sd[1], sd[2], sd[3]);
            }
        }
    }

#pragma unroll
    for (int i = 0; i < 4; i++) {
        int r = row_base + q * 4 + i;
        if (r < M) {
            float sc = SCALE ? rowscale[r] : 1.0f;
#pragma unroll
            for (int t = 0; t < NT; t++)
                Cbf[(size_t)r * NC + t * 16 + c] = f2bf(acc[t][i] * sc);
        }
    }
}

// ---------------------------------------------------------------------------
// MFMA GEMM with N=16, A already exact bf16 (K=KB*32). W2 split hi/lo ->
// 2 MFMAs, no A splitting needed. Fused s2 if SC2; bf16 output.
// ---------------------------------------------------------------------------
template <int KB, bool SCALE, bool SC2>
__global__ __launch_bounds__(256) void mfma_n16(const unsigned short* __restrict__ A,
                                                const unsigned short* __restrict__ Bhi,
                                                const unsigned short* __restrict__ Blo,
                                                unsigned short* __restrict__ Cbf,
                                                const float* __restrict__ rowscale,
                                                const float* __restrict__ a_s2,
                                                const float* __restrict__ a_d2,
                                                float* __restrict__ s2s,
                                                float* __restrict__ s2d, int M) {
    const int K = KB * 32;
    int tid = threadIdx.x;
    int w = tid >> 6, lane = tid & 63, q = lane >> 4, c = lane & 15;
    int row_base = blockIdx.x * 64 + w * 16;
    int ar = min(row_base + c, M - 1);
    const unsigned short* ap = A + (size_t)ar * K + q * 8;
    f32x4 acc = (f32x4){0.f, 0.f, 0.f, 0.f};
#pragma unroll
    for (int kb = 0; kb < KB; kb++) {
        short8 av = *(const short8*)(ap + kb * 32);
        size_t bo = ((size_t)kb * 64 + lane) * 8;
        short8 bh = *(const short8*)(Bhi + bo);
        short8 bl = *(const short8*)(Blo + bo);
        acc = __builtin_amdgcn_mfma_f32_16x16x32_bf16(av, bh, acc, 0, 0, 0);
        acc = __builtin_amdgcn_mfma_f32_16x16x32_bf16(av, bl, acc, 0, 0, 0);
    }
    if (SC2) {
#pragma unroll
        for (int i = 0; i < 4; i++) {
            float ps = acc[i] * a_s2[c];
            float pd = acc[i] * a_d2[c];
#pragma unroll
            for (int off = 1; off <= 8; off <<= 1) {
                ps += __shfl_xor(ps, off, 16);
                pd += __shfl_xor(pd, off, 16);
            }
            int r = row_base + q * 4 + i;
            if (c == i && r < M) {
                s2s[r] = ps;
                s2d[r] = pd;
            }
        }
    }
#pragma unroll
    for (int i = 0; i < 4; i++) {
        int r = row_base + q * 4 + i;
        if (r < M) {
            float sc = SCALE ? rowscale[r] : 1.0f;
            Cbf[(size_t)r * 16 + c] = f2bf(acc[i] * sc);
        }
    }
}

// ---------------------------------------------------------------------------
// GCN1 aggregation, h1 bf16, pre-scaled by dinv; out bf16. 2 loads in
// flight per lane (8 edges/iter across 4 groups).
// ---------------------------------------------------------------------------
__global__ __launch_bounds__(256) void gcn1_agg(const unsigned short* __restrict__ h,
                                                const int* __restrict__ rs,
                                                const int* __restrict__ col,
                                                const float* __restrict__ dinv,
                                                const float* __restrict__ b,
                                                unsigned short* __restrict__ out) {
    int wid = (blockIdx.x * 256 + threadIdx.x) >> 6;
    int lane = threadIdx.x & 63;
    if (wid >= NN) return;
    int g = lane >> 4;
    int cidx = (lane & 15) * 4;
    float di = dinv[wid];
    int beg = rs[wid], end = rs[wid + 1];
    float4 acc = make_float4(0.f, 0.f, 0.f, 0.f);

    for (int j0 = beg; j0 < end; j0 += 64) {
        int cnt = min(64, end - j0);
        int sreg = 0;
        if (lane < cnt) sreg = col[j0 + lane];
        for (int e = 0; e < cnt; e += 8) {
            int myE0 = e + g, myE1 = e + g + 4;
            int s0 = __shfl(sreg, myE0, 64);   // unconditional (round-2 lesson)
            int s1 = __shfl(sreg, myE1, 64);
            ushort4 v0 = make_ushort4(0, 0, 0, 0), v1 = make_ushort4(0, 0, 0, 0);
            if (myE0 < cnt) v0 = *(const ushort4*)(h + (size_t)s0 * HH + cidx);
            if (myE1 < cnt) v1 = *(const ushort4*)(h + (size_t)s1 * HH + cidx);
            acc.x += bf2f(v0.x) + bf2f(v1.x);
            acc.y += bf2f(v0.y) + bf2f(v1.y);
            acc.z += bf2f(v0.z) + bf2f(v1.z);
            acc.w += bf2f(v0.w) + bf2f(v1.w);
        }
    }
#pragma unroll
    for (int off = 16; off <= 32; off <<= 1) {
        acc.x += __shfl_xor(acc.x, off, 64);
        acc.y += __shfl_xor(acc.y, off, 64);
        acc.z += __shfl_xor(acc.z, off, 64);
        acc.w += __shfl_xor(acc.w, off, 64);
    }
    if (g == 0) {
        ushort4 sv = *(const ushort4*)(h + (size_t)wid * HH + cidx);
        float4 bv = *(const float4*)(b + cidx);
        ushort4 o;
        o.x = f2bf(fmaxf((acc.x + bf2f(sv.x)) * di + bv.x, 0.f));
        o.y = f2bf(fmaxf((acc.y + bf2f(sv.y)) * di + bv.y, 0.f));
        o.z = f2bf(fmaxf((acc.z + bf2f(sv.z)) * di + bv.z, 0.f));
        o.w = f2bf(fmaxf((acc.w + bf2f(sv.w)) * di + bv.w, 0.f));
        *(ushort4*)(out + (size_t)wid * HH + cidx) = o;
    }
}

// ---------------------------------------------------------------------------
// GAT1 aggregation: LDS-staged p/src; 4-edge unrolled gather (round-6:
// latency-bound at 9.6 B/cyc/CU with MLP=1 -> unroll for MLP=4).
// ---------------------------------------------------------------------------
__global__ __launch_bounds__(256) void gat1_agg(const unsigned short* __restrict__ hg,
                                                const int* __restrict__ rs,
                                                const int* __restrict__ col,
                                                const float* __restrict__ ssrc,
                                                const float* __restrict__ sdst,
                                                const float* __restrict__ b,
                                                unsigned short* __restrict__ out) {
    __shared__ int s_lds[4][64];
    __shared__ float p_lds[4][64 * 4];
    int tid = threadIdx.x;
    int w = tid >> 6, lane = tid & 63;
    int wid = blockIdx.x * 4 + w;       // grid exact: 12500*4 = NN
    int hh = lane >> 4;
    int* sl = s_lds[w];
    float* pl = p_lds[w];

    float4 sd4 = *(const float4*)(sdst + (size_t)wid * 4);
    float sdv[4] = {sd4.x, sd4.y, sd4.z, sd4.w};
    float4 sf4 = *(const float4*)(ssrc + (size_t)wid * 4);
    float sfv[4] = {sf4.x, sf4.y, sf4.z, sf4.w};
    float psf[4];
#pragma unroll
    for (int h = 0; h < 4; h++) {
        float e = sfv[h] + sdv[h];
        e = (e >= 0.f) ? e : 0.2f * e;
        psf[h] = __expf(e);
    }
    float pse = (hh & 2) ? ((hh & 1) ? psf[3] : psf[2]) : ((hh & 1) ? psf[1] : psf[0]);
    const unsigned short* hbase = hg + lane * 4;
    ushort4 hvs = *(const ushort4*)(hbase + (size_t)wid * 256);
    float4 acc;
    acc.x = bf2f(hvs.x) * pse; acc.y = bf2f(hvs.y) * pse;
    acc.z = bf2f(hvs.z) * pse; acc.w = bf2f(hvs.w) * pse;

    float lsum[4] = {0.f, 0.f, 0.f, 0.f};
    int beg = rs[wid], end = rs[wid + 1];
    for (int j0 = beg; j0 < end; j0 += 64) {
        int cnt = min(64, end - j0);
        if (lane < cnt) {
            int sreg = col[j0 + lane];
            float4 sv = *(const float4*)(ssrc + (size_t)sreg * 4);
            float svv[4] = {sv.x, sv.y, sv.z, sv.w};
            float pv[4];
#pragma unroll
            for (int h = 0; h < 4; h++) {
                float e = svv[h] + sdv[h];
                e = (e >= 0.f) ? e : 0.2f * e;
                pv[h] = __expf(e);
                lsum[h] += pv[h];
            }
            sl[lane] = sreg;
            *(float4*)&pl[lane * 4] = make_float4(pv[0], pv[1], pv[2], pv[3]);
        }
        // same-wave LDS write->read: DS pipe in-order per wave, no barrier
        int e = 0;
        for (; e + 4 <= cnt; e += 4) {
            int s0 = sl[e], s1 = sl[e + 1], s2 = sl[e + 2], s3 = sl[e + 3];
            float p0 = pl[e * 4 + hh], p1 = pl[(e + 1) * 4 + hh];
            float p2 = pl[(e + 2) * 4 + hh], p3 = pl[(e + 3) * 4 + hh];
            ushort4 h0 = *(const ushort4*)(hbase + (size_t)s0 * 256);
            ushort4 h1 = *(const ushort4*)(hbase + (size_t)s1 * 256);
            ushort4 h2 = *(const ushort4*)(hbase + (size_t)s2 * 256);
            ushort4 h3 = *(const ushort4*)(hbase + (size_t)s3 * 256);
            acc.x += bf2f(h0.x) * p0; acc.y += bf2f(h0.y) * p0;
            acc.z += bf2f(h0.z) * p0; acc.w += bf2f(h0.w) * p0;
            acc.x += bf2f(h1.x) * p1; acc.y += bf2f(h1.y) * p1;
            acc.z += bf2f(h1.z) * p1; acc.w += bf2f(h1.w) * p1;
            acc.x += bf2f(h2.x) * p2; acc.y += bf2f(h2.y) * p2;
            acc.z += bf2f(h2.z) * p2; acc.w += bf2f(h2.w) * p2;
            acc.x += bf2f(h3.x) * p3; acc.y += bf2f(h3.y) * p3;
            acc.z += bf2f(h3.z) * p3; acc.w += bf2f(h3.w) * p3;
        }
        for (; e < cnt; e++) {
            int s = sl[e];
            float p = pl[e * 4 + hh];
            ushort4 hv = *(const ushort4*)(hbase + (size_t)s * 256);
            acc.x += bf2f(hv.x) * p; acc.y += bf2f(hv.y) * p;
            acc.z += bf2f(hv.z) * p; acc.w += bf2f(hv.w) * p;
        }
    }
#pragma unroll
    for (int h = 0; h < 4; h++) {
        float v = lsum[h];
        for (int off = 32; off >= 1; off >>= 1) v += __shfl_xor(v, off, 64);
        lsum[h] = v + psf[h];
    }
    float lt = (hh & 2) ? ((hh & 1) ? lsum[3] : lsum[2]) : ((hh & 1) ? lsum[1] : lsum[0]);
    float li = 1.0f / lt;
    float4 bv = *(const float4*)(b + lane * 4);
    ushort4 o;
    o.x = f2bf(fmaxf(acc.x * li + bv.x, 0.f));
    o.y = f2bf(fmaxf(acc.y * li + bv.y, 0.f));
    o.z = f2bf(fmaxf(acc.z * li + bv.z, 0.f));
    o.w = f2bf(fmaxf(acc.w * li + bv.w, 0.f));
    *(ushort4*)(out + (size_t)wid * 256 + lane * 4) = o;
}

// ---------------------------------------------------------------------------
// Final aggregation: fused GCN2 + GAT2, bf16 inputs, 4-edge unroll for MLP.
// ---------------------------------------------------------------------------
__global__ __launch_bounds__(256) void final_agg(const unsigned short* __restrict__ h2,
                                                 const unsigned short* __restrict__ h2g,
                                                 const int* __restrict__ rs,
                                                 const int* __restrict__ col,
                                                 const float* __restrict__ dinv,
                                                 const float* __restrict__ s2s,
                                                 const float* __restrict__ s2d,
                                                 const float* __restrict__ bg2,
                                                 const float* __restrict__ bga2,
                                                 float* __restrict__ out) {
    int t = blockIdx.x * 256 + threadIdx.x;
    int node = t >> 4;
    int c = t & 15;
    float di = dinv[node];
    float sd = s2d[node];
    float es = s2s[node] + sd;
    es = (es >= 0.f) ? es : 0.2f * es;
    float psf = __expf(es);
    float accg = bf2f(h2[(size_t)node * 16 + c]);
    float acca = bf2f(h2g[(size_t)node * 16 + c]) * psf;
    float lp = 0.f;
    int beg = rs[node], end = rs[node + 1];
    for (int j0 = beg; j0 < end; j0 += 16) {
        int cnt = min(16, end - j0);
        int sreg = 0;
        float pr = 0.f;
        if (c < cnt) {
            sreg = col[j0 + c];
            float e = s2s[sreg] + sd;
            e = (e >= 0.f) ? e : 0.2f * e;
            pr = __expf(e);
            lp += pr;
        }
        for (int e = 0; e < cnt; e += 4) {
            int si[4];
            float pi[4];
#pragma unroll
            for (int u = 0; u < 4; u++) {
                si[u] = __shfl(sreg, (e + u) & 15, 16);  // sources active in-group
                pi[u] = __shfl(pr, (e + u) & 15, 16);
            }
            unsigned short g0[4], a0[4];
#pragma unroll
            for (int u = 0; u < 4; u++) {
                g0[u] = h2[(size_t)si[u] * 16 + c];      // index always valid
                a0[u] = h2g[(size_t)si[u] * 16 + c];
            }
#pragma unroll
            for (int u = 0; u < 4; u++) {
                if (e + u < cnt) {
                    accg += bf2f(g0[u]);
                    acca += bf2f(a0[u]) * pi[u];
                }
            }
        }
    }
    for (int off = 8; off >= 1; off >>= 1) lp += __shfl_xor(lp, off, 16);
    float l = lp + psf;
    out[(size_t)node * 32 + c] = accg * di + bg2[c];
    out[(size_t)node * 32 + 16 + c] = acca / l + bga2[c];
}

// ---------------------------------------------------------------------------
// Launch
// ---------------------------------------------------------------------------
extern "C" void kernel_launch(void* const* d_in, const int* in_sizes, int n_in,
                              void* d_out, int out_size, void* d_ws, size_t ws_size,
                              hipStream_t stream) {
    const float* x      = (const float*)d_in[0];
    const int*   ei     = (const int*)d_in[1];
    const float* Wg1    = (const float*)d_in[2];
    const float* bg1    = (const float*)d_in[3];
    const float* Wg2    = (const float*)d_in[4];
    const float* bg2    = (const float*)d_in[5];
    const float* Wgat1  = (const float*)d_in[6];
    const float* a_src1 = (const float*)d_in[7];
    const float* a_dst1 = (const float*)d_in[8];
    const float* bgat1  = (const float*)d_in[9];
    const float* Wgat2  = (const float*)d_in[10];
    const float* a_src2 = (const float*)d_in[11];
    const float* a_dst2 = (const float*)d_in[12];
    const float* bgat2  = (const float*)d_in[13];
    float* out = (float*)d_out;

    const int* e_src = ei;
    const int* e_dst = ei + EE;

    char* wsb = (char*)d_ws;
    size_t o = 0;
    auto alloc = [&](size_t bytes) -> void* {
        void* p = wsb + o;
        o += (bytes + 255) & ~(size_t)255;
        return p;
    };
    float* dinv            = (float*)alloc(NN * 4);
    float* ssrc1           = (float*)alloc((size_t)NN * 16);
    float* sdst1           = (float*)alloc((size_t)NN * 16);
    unsigned short* h1b    = (unsigned short*)alloc((size_t)NN * HH * 2);
    unsigned short* xg1    = (unsigned short*)alloc((size_t)NN * HH * 2);
    unsigned short* h2b    = (unsigned short*)alloc((size_t)NN * 16 * 2);
    unsigned short* hgb    = (unsigned short*)alloc((size_t)NN * 256 * 2);
    unsigned short* xgat1  = (unsigned short*)alloc((size_t)NN * 256 * 2);
    unsigned short* h2gb   = (unsigned short*)alloc((size_t)NN * 16 * 2);
    float* s2src           = (float*)alloc(NN * 4);
    float* s2dst           = (float*)alloc(NN * 4);
    unsigned short* bhi1   = (unsigned short*)alloc(256 * 64 * 2);
    unsigned short* blo1   = (unsigned short*)alloc(256 * 64 * 2);
    unsigned short* bhi2   = (unsigned short*)alloc(256 * 256 * 2);
    unsigned short* blo2   = (unsigned short*)alloc(256 * 256 * 2);
    unsigned short* bhiG2  = (unsigned short*)alloc(64 * 16 * 2);
    unsigned short* bloG2  = (unsigned short*)alloc(64 * 16 * 2);
    unsigned short* bhiA2  = (unsigned short*)alloc(256 * 16 * 2);
    unsigned short* bloA2  = (unsigned short*)alloc(256 * 16 * 2);
    int* cnt               = (int*)alloc(NN * 4);
    int* rowstart          = (int*)alloc((NN + 1) * 4);
    int* cursor            = (int*)alloc(NN * 4);
    int* colarr            = (int*)alloc((size_t)EE * 4);
    int* partial           = (int*)alloc(256 * 4);
    int* blockoff          = (int*)alloc(256 * 4);

    const int TB = 256;
    const int NB = (NN + 255) / 256;
    // CSR build + weight packing
    k_zero_int<<<(NN + TB - 1) / TB, TB, 0, stream>>>(cnt, NN);
    k_count<<<(EE + TB - 1) / TB, TB, 0, stream>>>(e_dst, cnt, EE);
    k_scan_a<<<NB, TB, 0, stream>>>(cnt, partial, NN);
    k_scan_b<<<1, TB, 0, stream>>>(partial, blockoff, rowstart + NN, NB);
    k_scan_c<<<NB, TB, 0, stream>>>(cnt, blockoff, rowstart, cursor, dinv, NN);
    k_fill<<<(EE + TB - 1) / TB, TB, 0, stream>>>(e_src, e_dst, cursor, colarr, EE);
    k_pack_w<8, 4><<<(8 * 4 * 64 + TB - 1) / TB, TB, 0, stream>>>(Wg1, bhi1, blo1);
    k_pack_w<8, 16><<<(8 * 16 * 64 + TB - 1) / TB, TB, 0, stream>>>(Wgat1, bhi2, blo2);
    k_pack_w<2, 1><<<1, TB, 0, stream>>>(Wg2, bhiG2, bloG2);
    k_pack_w<8, 1><<<2, TB, 0, stream>>>(Wgat2, bhiA2, bloA2);

    const int GB = (NN + 63) / 64;
    const int G16 = (NN * 16) / 256;  // exact: 3125

    // GCN path
    mfma_gemm<4, true, false><<<GB, TB, 0, stream>>>(x, bhi1, blo1, h1b, dinv,
                                                     nullptr, nullptr, nullptr, nullptr, NN);
    gcn1_agg<<<(NN * 64) / TB, TB, 0, stream>>>(h1b, rowstart, colarr, dinv, bg1, xg1);
    mfma_n16<2, true, false><<<GB, TB, 0, stream>>>(xg1, bhiG2, bloG2, h2b, dinv,
                                                    nullptr, nullptr, nullptr, nullptr, NN);

    // GAT path
    mfma_gemm<16, false, true><<<GB, TB, 0, stream>>>(x, bhi2, blo2, hgb, nullptr,
                                                      a_src1, a_dst1, ssrc1, sdst1, NN);
    gat1_agg<<<NN / 4, TB, 0, stream>>>(hgb, rowstart, colarr, ssrc1, sdst1, bgat1, xgat1);
    mfma_n16<8, false, true><<<GB, TB, 0, stream>>>(xgat1, bhiA2, bloA2, h2gb, nullptr,
                                                    a_src2, a_dst2, s2src, s2dst, NN);

    // Fused GCN2+GAT2 aggregation -> d_out
    final_agg<<<G16, TB, 0, stream>>>(h2b, h2gb, rowstart, colarr, dinv,
                                      s2src, s2dst, bg2, bgat2, out);
}